// Round 3
// baseline (4663.821 us; speedup 1.0000x reference)
//
#include <hip/hip_runtime.h>

#define NN 100000
#define NE 1600000
#define HD 128
#define NL 3
#define NG 1024
#define BN_EPS 1e-5f

static inline int cdiv(int a, int b) { return (a + b - 1) / b; }

// ---------------- embedding gather: x[i,:] = table[z[i],:] ----------------
__global__ __launch_bounds__(256) void embed_kernel(const int* __restrict__ z,
    const float* __restrict__ table, float* __restrict__ x) {
  int t = blockIdx.x * 256 + threadIdx.x;            // over NN*32 float4s
  if (t >= NN * 32) return;
  int row = t >> 5, c4 = (t & 31) << 2;
  int zi = z[row];
  *(float4*)(x + (size_t)row * HD + c4) =
      *(const float4*)(table + (size_t)zi * HD + c4);
}

// ------------- copy x rows (stride-aware) into agg (self term) -------------
__global__ __launch_bounds__(256) void copy_rows_kernel(const float* __restrict__ src,
    int sstride, float* __restrict__ dst) {
  int t = blockIdx.x * 256 + threadIdx.x;
  if (t >= NN * 32) return;
  int row = t >> 5, c4 = (t & 31) << 2;
  *(float4*)(dst + (size_t)row * HD + c4) =
      *(const float4*)(src + (size_t)row * sstride + c4);
}

// ---------------- edge scatter: agg[dst] += x[src] (atomics) ---------------
__global__ __launch_bounds__(256) void edge_kernel(const int* __restrict__ srcI,
    const int* __restrict__ dstI, const float* __restrict__ x, int xstride,
    float* __restrict__ agg) {
  int e = blockIdx.x * 4 + (threadIdx.x >> 6);       // one wave per edge
  if (e >= NE) return;
  int lane = threadIdx.x & 63;
  int s = srcI[e], d = dstI[e];
  float2 v = *(const float2*)(x + (size_t)s * xstride + lane * 2);
  float* p = agg + (size_t)d * HD + lane * 2;
  atomicAdd(p, v.x);
  atomicAdd(p + 1, v.y);
}

// ------------- C = relu(A @ B + bias), A:[M][128], B:[128][128] ------------
__global__ __launch_bounds__(256) void gemm_relu_kernel(
    const float* __restrict__ A, const float* __restrict__ B,
    const float* __restrict__ bias, float* __restrict__ C, int M) {
  __shared__ float As[128][65];   // k-major (transposed), +1 pad
  __shared__ float Bs[32][128];   // one K-chunk of B
  const int tid = threadIdx.x;
  const int row0 = blockIdx.x * 64;

  // stage A tile 64 rows x 128 k, transposed to k-major
  #pragma unroll
  for (int i = 0; i < 8; ++i) {
    int f = tid + i * 256;        // float4 index over [64 rows][32 kquads]
    int row = f >> 5;
    int kq = (f & 31) << 2;
    int gr = row0 + row;
    float4 v = make_float4(0.f, 0.f, 0.f, 0.f);
    if (gr < M) v = *(const float4*)(A + (size_t)gr * HD + kq);
    As[kq + 0][row] = v.x; As[kq + 1][row] = v.y;
    As[kq + 2][row] = v.z; As[kq + 3][row] = v.w;
  }

  const int colbase = (tid & 15) << 2;   // cols {colbase..+3} and {+64..+67}
  const int rowbase = (tid >> 4) << 2;   // 4 rows
  float acc[4][8] = {};

  for (int kc = 0; kc < 4; ++kc) {
    __syncthreads();
    #pragma unroll
    for (int i = 0; i < 4; ++i) {
      int f = tid + i * 256;      // float4 idx over [32 k][32 cquads]
      int k = f >> 5;
      int c4 = (f & 31) << 2;
      *(float4*)(&Bs[k][c4]) = *(const float4*)(B + (size_t)(kc * 32 + k) * HD + c4);
    }
    __syncthreads();
    #pragma unroll
    for (int k = 0; k < 32; ++k) {
      const int kk = kc * 32 + k;
      float a0 = As[kk][rowbase + 0];
      float a1 = As[kk][rowbase + 1];
      float a2 = As[kk][rowbase + 2];
      float a3 = As[kk][rowbase + 3];
      float4 bl = *(const float4*)(&Bs[k][colbase]);
      float4 bh = *(const float4*)(&Bs[k][colbase + 64]);
      acc[0][0] += a0 * bl.x; acc[0][1] += a0 * bl.y; acc[0][2] += a0 * bl.z; acc[0][3] += a0 * bl.w;
      acc[0][4] += a0 * bh.x; acc[0][5] += a0 * bh.y; acc[0][6] += a0 * bh.z; acc[0][7] += a0 * bh.w;
      acc[1][0] += a1 * bl.x; acc[1][1] += a1 * bl.y; acc[1][2] += a1 * bl.z; acc[1][3] += a1 * bl.w;
      acc[1][4] += a1 * bh.x; acc[1][5] += a1 * bh.y; acc[1][6] += a1 * bh.z; acc[1][7] += a1 * bh.w;
      acc[2][0] += a2 * bl.x; acc[2][1] += a2 * bl.y; acc[2][2] += a2 * bl.z; acc[2][3] += a2 * bl.w;
      acc[2][4] += a2 * bh.x; acc[2][5] += a2 * bh.y; acc[2][6] += a2 * bh.z; acc[2][7] += a2 * bh.w;
      acc[3][0] += a3 * bl.x; acc[3][1] += a3 * bl.y; acc[3][2] += a3 * bl.z; acc[3][3] += a3 * bl.w;
      acc[3][4] += a3 * bh.x; acc[3][5] += a3 * bh.y; acc[3][6] += a3 * bh.z; acc[3][7] += a3 * bh.w;
    }
  }

  float4 bvl = *(const float4*)(bias + colbase);
  float4 bvh = *(const float4*)(bias + colbase + 64);
  #pragma unroll
  for (int r = 0; r < 4; ++r) {
    int gr = row0 + rowbase + r;
    if (gr < M) {
      float4 o;
      o.x = fmaxf(acc[r][0] + bvl.x, 0.f);
      o.y = fmaxf(acc[r][1] + bvl.y, 0.f);
      o.z = fmaxf(acc[r][2] + bvl.z, 0.f);
      o.w = fmaxf(acc[r][3] + bvl.w, 0.f);
      *(float4*)(C + (size_t)gr * HD + colbase) = o;
      o.x = fmaxf(acc[r][4] + bvh.x, 0.f);
      o.y = fmaxf(acc[r][5] + bvh.y, 0.f);
      o.z = fmaxf(acc[r][6] + bvh.z, 0.f);
      o.w = fmaxf(acc[r][7] + bvh.w, 0.f);
      *(float4*)(C + (size_t)gr * HD + colbase + 64) = o;
    }
  }
}

// ----------------------------- BN statistics ------------------------------
__global__ void zero_kernel(float* p) { p[threadIdx.x] = 0.f; }

__global__ __launch_bounds__(256) void bn_stats_kernel(const float* __restrict__ h,
    float* __restrict__ sums) {
  int tid = threadIdx.x;
  int col = tid & (HD - 1);
  int rowoff = tid >> 7;                 // 0..1
  float s = 0.f, sq = 0.f;
  for (int r = blockIdx.x * 2 + rowoff; r < NN; r += gridDim.x * 2) {
    float v = h[(size_t)r * HD + col];
    s += v; sq += v * v;
  }
  __shared__ float bs[256], bq[256];
  bs[tid] = s; bq[tid] = sq;
  __syncthreads();
  if (tid < HD) {
    atomicAdd(&sums[col], bs[tid] + bs[tid + HD]);
    atomicAdd(&sums[HD + col], bq[tid] + bq[tid + HD]);
  }
}

__global__ void bn_finalize_kernel(const float* __restrict__ sums,
    const float* __restrict__ gamma, const float* __restrict__ beta,
    float* __restrict__ ss) {
  int c = threadIdx.x;                   // 128 threads
  float mu = sums[c] * (1.f / NN);
  float var = sums[HD + c] * (1.f / NN) - mu * mu;
  float sc = gamma[c] * rsqrtf(var + BN_EPS);
  ss[c] = sc;
  ss[HD + c] = beta[c] - mu * sc;
}

__global__ __launch_bounds__(256) void bn_apply_kernel(const float* __restrict__ h,
    const float* __restrict__ ss, float* __restrict__ featl) {
  int t = blockIdx.x * 256 + threadIdx.x;
  if (t >= NN * 32) return;
  int row = t >> 5, c4 = (t & 31) << 2;
  float4 v = *(const float4*)(h + (size_t)row * HD + c4);
  float4 sc = *(const float4*)(ss + c4);
  float4 sh = *(const float4*)(ss + HD + c4);
  float4 o;
  o.x = v.x * sc.x + sh.x;
  o.y = v.y * sc.y + sh.y;
  o.z = v.z * sc.z + sh.z;
  o.w = v.w * sc.w + sh.w;
  *(float4*)(featl + (size_t)row * (NL * HD) + c4) = o;
}

// --------------------- mean pool over sorted batch ids ---------------------
__device__ __forceinline__ int lbound(const int* __restrict__ b, int val) {
  int lo = 0, hi = NN;
  while (lo < hi) { int m = (lo + hi) >> 1; if (b[m] < val) lo = m + 1; else hi = m; }
  return lo;
}

__global__ __launch_bounds__(384) void pool_kernel(const int* __restrict__ batch,
    const float* __restrict__ feat, float* __restrict__ pooled) {
  int g = blockIdx.x;
  int lo = lbound(batch, g), hi = lbound(batch, g + 1);
  float s = 0.f;
  for (int r = lo; r < hi; ++r) s += feat[(size_t)r * (NL * HD) + threadIdx.x];
  float inv = 1.f / (float)max(hi - lo, 1);
  pooled[(size_t)g * (NL * HD) + threadIdx.x] = s * inv;
}

// ------------------------------- final MLP --------------------------------
__global__ __launch_bounds__(128) void mlp_kernel(const float* __restrict__ pooled,
    const float* __restrict__ W1, const float* __restrict__ b1,
    const float* __restrict__ W2, const float* __restrict__ b2,
    float* __restrict__ out) {
  int g = blockIdx.x, c = threadIdx.x;
  const float* p = pooled + (size_t)g * (NL * HD);
  float acc = b1[c];
  #pragma unroll 4
  for (int k = 0; k < NL * HD; ++k) acc = fmaf(p[k], W1[(size_t)k * HD + c], acc);
  acc = fmaxf(acc, 0.f);
  float prod = acc * W2[c];
  #pragma unroll
  for (int off = 32; off > 0; off >>= 1) prod += __shfl_xor(prod, off, 64);
  __shared__ float part[2];
  if ((c & 63) == 0) part[c >> 6] = prod;
  __syncthreads();
  if (c == 0) out[g] = part[0] + part[1] + b2[0];
}

// -------------------------------- launcher --------------------------------
extern "C" void kernel_launch(void* const* d_in, const int* in_sizes, int n_in,
                              void* d_out, int out_size, void* d_ws, size_t ws_size,
                              hipStream_t stream) {
  (void)in_sizes; (void)n_in; (void)out_size; (void)ws_size;
  const int*   z     = (const int*)d_in[0];
  const int*   ei    = (const int*)d_in[1];
  const int*   batch = (const int*)d_in[2];
  const float* ztab  = (const float*)d_in[3];
  const float* W1    = (const float*)d_in[4];
  const float* b1    = (const float*)d_in[5];
  const float* W2    = (const float*)d_in[6];
  const float* b2    = (const float*)d_in[7];
  const float* gamma = (const float*)d_in[8];
  const float* beta  = (const float*)d_in[9];
  const float* l1W   = (const float*)d_in[10];
  const float* l1b   = (const float*)d_in[11];
  const float* l2W   = (const float*)d_in[12];
  const float* l2b   = (const float*)d_in[13];
  float* out = (float*)d_out;

  char* w = (char*)d_ws;
  float* bufA   = (float*)w; w += (size_t)NN * HD * 4;
  float* bufB   = (float*)w; w += (size_t)NN * HD * 4;
  float* feat   = (float*)w; w += (size_t)NN * (NL * HD) * 4;
  float* pooled = (float*)w; w += (size_t)NG * (NL * HD) * 4;
  float* sums   = (float*)w; w += 256 * 4;
  float* sshift = (float*)w; w += 256 * 4;

  const int* srcI = ei;
  const int* dstI = ei + NE;

  dim3 blk(256);
  const int g_nh = cdiv(NN * 32, 256);   // 12500
  embed_kernel<<<g_nh, blk, 0, stream>>>(z, ztab, bufA);

  for (int l = 0; l < NL; ++l) {
    const float* xin;
    int xstride;
    if (l == 0) { xin = bufA; xstride = HD; }
    else        { xin = feat + (l - 1) * HD; xstride = NL * HD; }
    float* aggbuf = (l & 1) ? bufA : bufB;   // l=0: B, l=1: A, l=2: B
    float* tmpbuf = (l & 1) ? bufB : bufA;

    copy_rows_kernel<<<g_nh, blk, 0, stream>>>(xin, xstride, aggbuf);
    edge_kernel<<<NE / 4, blk, 0, stream>>>(srcI, dstI, xin, xstride, aggbuf);
    gemm_relu_kernel<<<cdiv(NN, 64), blk, 0, stream>>>(aggbuf, W1 + (size_t)l * HD * HD,
                                                       b1 + l * HD, tmpbuf, NN);
    gemm_relu_kernel<<<cdiv(NN, 64), blk, 0, stream>>>(tmpbuf, W2 + (size_t)l * HD * HD,
                                                       b2 + l * HD, aggbuf, NN);
    zero_kernel<<<1, 256, 0, stream>>>(sums);
    bn_stats_kernel<<<512, blk, 0, stream>>>(aggbuf, sums);
    bn_finalize_kernel<<<1, 128, 0, stream>>>(sums, gamma + l * HD, beta + l * HD, sshift);
    bn_apply_kernel<<<g_nh, blk, 0, stream>>>(aggbuf, sshift, feat + l * HD);
  }

  pool_kernel<<<NG, 384, 0, stream>>>(batch, feat, pooled);
  mlp_kernel<<<NG, 128, 0, stream>>>(pooled, l1W, l1b, l2W, l2b, out);
}

// Round 8
// 1398.363 us; speedup vs baseline: 3.3352x; 3.3352x over previous
//
#include <hip/hip_runtime.h>

#define NN 100000
#define NE 1600000
#define HD 128
#define NL 3
#define NG 1024
#define BN_EPS 1e-5f
#define SCAN_CHUNK 1024

static inline int cdiv(int a, int b) { return (a + b - 1) / b; }

// ---------------- embedding gather: x[i,:] = table[z[i],:] ----------------
__global__ __launch_bounds__(256) void embed_kernel(const int* __restrict__ z,
    const float* __restrict__ table, float* __restrict__ x) {
  int t = blockIdx.x * 256 + threadIdx.x;            // over NN*32 float4s
  if (t >= NN * 32) return;
  int row = t >> 5, c4 = (t & 31) << 2;
  int zi = z[row];
  *(float4*)(x + (size_t)row * HD + c4) =
      *(const float4*)(table + (size_t)zi * HD + c4);
}

// --------------------------- CSR build pipeline ---------------------------
__global__ __launch_bounds__(256) void zero_counts_kernel(int* __restrict__ cnt) {
  int t = blockIdx.x * 256 + threadIdx.x;
  if (t < NN) cnt[t] = 0;
}

__global__ __launch_bounds__(256) void hist_kernel(const int* __restrict__ dstI,
    int* __restrict__ cnt) {
  int e = blockIdx.x * 256 + threadIdx.x;
  if (e < NE) atomicAdd(&cnt[dstI[e]], 1);
}

// block-local exclusive scan of SCAN_CHUNK elements; bsums gets chunk total
__global__ __launch_bounds__(256) void scan_block_kernel(const int* __restrict__ cnt,
    int* __restrict__ rowptr, int* __restrict__ bsums) {
  __shared__ int sh[SCAN_CHUNK];
  __shared__ int ts[256];
  int base = blockIdx.x * SCAN_CHUNK;
  for (int i = threadIdx.x; i < SCAN_CHUNK; i += 256)
    sh[i] = (base + i < NN) ? cnt[base + i] : 0;
  __syncthreads();
  int t4 = threadIdx.x * 4;
  int a0 = sh[t4], a1 = sh[t4 + 1], a2 = sh[t4 + 2], a3 = sh[t4 + 3];
  int tsum = a0 + a1 + a2 + a3;
  ts[threadIdx.x] = tsum;
  __syncthreads();
  for (int off = 1; off < 256; off <<= 1) {
    int v = ts[threadIdx.x];
    int u = (threadIdx.x >= off) ? ts[threadIdx.x - off] : 0;
    __syncthreads();
    ts[threadIdx.x] = v + u;
    __syncthreads();
  }
  int texcl = ts[threadIdx.x] - tsum;
  sh[t4] = texcl;
  sh[t4 + 1] = texcl + a0;
  sh[t4 + 2] = texcl + a0 + a1;
  sh[t4 + 3] = texcl + a0 + a1 + a2;
  __syncthreads();
  for (int i = threadIdx.x; i < SCAN_CHUNK; i += 256) {
    int g = base + i;
    if (g < NN) rowptr[g] = sh[i];
  }
  if (threadIdx.x == 255) bsums[blockIdx.x] = ts[255];
}

__global__ void scan_bsums_kernel(int* __restrict__ bsums, int nb) {
  if (threadIdx.x == 0) {
    int run = 0;
    for (int i = 0; i < nb; ++i) { int v = bsums[i]; bsums[i] = run; run += v; }
  }
}

__global__ __launch_bounds__(256) void scan_add_kernel(int* __restrict__ rowptr,
    const int* __restrict__ bsums, int* __restrict__ fill_off) {
  int t = blockIdx.x * 256 + threadIdx.x;
  if (t < NN) {
    int v = rowptr[t] + bsums[t / SCAN_CHUNK];
    rowptr[t] = v;
    fill_off[t] = v;
  }
  if (t == 0) rowptr[NN] = NE;
}

__global__ __launch_bounds__(256) void fill_kernel(const int* __restrict__ srcI,
    const int* __restrict__ dstI, int* __restrict__ fill_off, int* __restrict__ esrc) {
  int e = blockIdx.x * 256 + threadIdx.x;
  if (e >= NE) return;
  int d = dstI[e];
  int pos = atomicAdd(&fill_off[d], 1);
  esrc[pos] = srcI[e];
}

// ------- CSR gather aggregation: agg[n] = x[n] + sum_{s in N(n)} x[s] -------
__global__ __launch_bounds__(256) void agg_kernel(const int* __restrict__ rowptr,
    const int* __restrict__ esrc, const float* __restrict__ xin, int xstride,
    float* __restrict__ agg) {
  int n = blockIdx.x * 4 + (threadIdx.x >> 6);       // one wave per node
  if (n >= NN) return;
  int lane = threadIdx.x & 63;
  int lo = rowptr[n], hi = rowptr[n + 1];
  float2 acc = *(const float2*)(xin + (size_t)n * xstride + lane * 2);  // self
  for (int j = lo; j < hi; ++j) {
    int s = esrc[j];
    float2 v = *(const float2*)(xin + (size_t)s * xstride + lane * 2);
    acc.x += v.x; acc.y += v.y;
  }
  *(float2*)(agg + (size_t)n * HD + lane * 2) = acc;
}

// ------------- C = relu(A @ B + bias), A:[M][128], B:[128][128] ------------
__global__ __launch_bounds__(256) void gemm_relu_kernel(
    const float* __restrict__ A, const float* __restrict__ B,
    const float* __restrict__ bias, float* __restrict__ C, int M) {
  __shared__ float As[128][65];   // k-major (transposed), +1 pad
  __shared__ float Bs[32][128];   // one K-chunk of B
  const int tid = threadIdx.x;
  const int row0 = blockIdx.x * 64;

  #pragma unroll
  for (int i = 0; i < 8; ++i) {
    int f = tid + i * 256;
    int row = f >> 5;
    int kq = (f & 31) << 2;
    int gr = row0 + row;
    float4 v = make_float4(0.f, 0.f, 0.f, 0.f);
    if (gr < M) v = *(const float4*)(A + (size_t)gr * HD + kq);
    As[kq + 0][row] = v.x; As[kq + 1][row] = v.y;
    As[kq + 2][row] = v.z; As[kq + 3][row] = v.w;
  }

  const int colbase = (tid & 15) << 2;
  const int rowbase = (tid >> 4) << 2;
  float acc[4][8] = {};

  for (int kc = 0; kc < 4; ++kc) {
    __syncthreads();
    #pragma unroll
    for (int i = 0; i < 4; ++i) {
      int f = tid + i * 256;
      int k = f >> 5;
      int c4 = (f & 31) << 2;
      *(float4*)(&Bs[k][c4]) = *(const float4*)(B + (size_t)(kc * 32 + k) * HD + c4);
    }
    __syncthreads();
    #pragma unroll
    for (int k = 0; k < 32; ++k) {
      const int kk = kc * 32 + k;
      float a0 = As[kk][rowbase + 0];
      float a1 = As[kk][rowbase + 1];
      float a2 = As[kk][rowbase + 2];
      float a3 = As[kk][rowbase + 3];
      float4 bl = *(const float4*)(&Bs[k][colbase]);
      float4 bh = *(const float4*)(&Bs[k][colbase + 64]);
      acc[0][0] += a0 * bl.x; acc[0][1] += a0 * bl.y; acc[0][2] += a0 * bl.z; acc[0][3] += a0 * bl.w;
      acc[0][4] += a0 * bh.x; acc[0][5] += a0 * bh.y; acc[0][6] += a0 * bh.z; acc[0][7] += a0 * bh.w;
      acc[1][0] += a1 * bl.x; acc[1][1] += a1 * bl.y; acc[1][2] += a1 * bl.z; acc[1][3] += a1 * bl.w;
      acc[1][4] += a1 * bh.x; acc[1][5] += a1 * bh.y; acc[1][6] += a1 * bh.z; acc[1][7] += a1 * bh.w;
      acc[2][0] += a2 * bl.x; acc[2][1] += a2 * bl.y; acc[2][2] += a2 * bl.z; acc[2][3] += a2 * bl.w;
      acc[2][4] += a2 * bh.x; acc[2][5] += a2 * bh.y; acc[2][6] += a2 * bh.z; acc[2][7] += a2 * bh.w;
      acc[3][0] += a3 * bl.x; acc[3][1] += a3 * bl.y; acc[3][2] += a3 * bl.z; acc[3][3] += a3 * bl.w;
      acc[3][4] += a3 * bh.x; acc[3][5] += a3 * bh.y; acc[3][6] += a3 * bh.z; acc[3][7] += a3 * bh.w;
    }
  }

  float4 bvl = *(const float4*)(bias + colbase);
  float4 bvh = *(const float4*)(bias + colbase + 64);
  #pragma unroll
  for (int r = 0; r < 4; ++r) {
    int gr = row0 + rowbase + r;
    if (gr < M) {
      float4 o;
      o.x = fmaxf(acc[r][0] + bvl.x, 0.f);
      o.y = fmaxf(acc[r][1] + bvl.y, 0.f);
      o.z = fmaxf(acc[r][2] + bvl.z, 0.f);
      o.w = fmaxf(acc[r][3] + bvl.w, 0.f);
      *(float4*)(C + (size_t)gr * HD + colbase) = o;
      o.x = fmaxf(acc[r][4] + bvh.x, 0.f);
      o.y = fmaxf(acc[r][5] + bvh.y, 0.f);
      o.z = fmaxf(acc[r][6] + bvh.z, 0.f);
      o.w = fmaxf(acc[r][7] + bvh.w, 0.f);
      *(float4*)(C + (size_t)gr * HD + colbase + 64) = o;
    }
  }
}

// ----------------------------- BN statistics ------------------------------
__global__ void zero_kernel(float* p) { p[threadIdx.x] = 0.f; }

__global__ __launch_bounds__(256) void bn_stats_kernel(const float* __restrict__ h,
    float* __restrict__ sums) {
  int tid = threadIdx.x;
  int col = tid & (HD - 1);
  int rowoff = tid >> 7;
  float s = 0.f, sq = 0.f;
  for (int r = blockIdx.x * 2 + rowoff; r < NN; r += gridDim.x * 2) {
    float v = h[(size_t)r * HD + col];
    s += v; sq += v * v;
  }
  __shared__ float bs[256], bq[256];
  bs[tid] = s; bq[tid] = sq;
  __syncthreads();
  if (tid < HD) {
    atomicAdd(&sums[col], bs[tid] + bs[tid + HD]);
    atomicAdd(&sums[HD + col], bq[tid] + bq[tid + HD]);
  }
}

__global__ void bn_finalize_kernel(const float* __restrict__ sums,
    const float* __restrict__ gamma, const float* __restrict__ beta,
    float* __restrict__ ss) {
  int c = threadIdx.x;
  float mu = sums[c] * (1.f / NN);
  float var = sums[HD + c] * (1.f / NN) - mu * mu;
  float sc = gamma[c] * rsqrtf(var + BN_EPS);
  ss[c] = sc;
  ss[HD + c] = beta[c] - mu * sc;
}

__global__ __launch_bounds__(256) void bn_apply_kernel(const float* __restrict__ h,
    const float* __restrict__ ss, float* __restrict__ featl) {
  int t = blockIdx.x * 256 + threadIdx.x;
  if (t >= NN * 32) return;
  int row = t >> 5, c4 = (t & 31) << 2;
  float4 v = *(const float4*)(h + (size_t)row * HD + c4);
  float4 sc = *(const float4*)(ss + c4);
  float4 sh = *(const float4*)(ss + HD + c4);
  float4 o;
  o.x = v.x * sc.x + sh.x;
  o.y = v.y * sc.y + sh.y;
  o.z = v.z * sc.z + sh.z;
  o.w = v.w * sc.w + sh.w;
  *(float4*)(featl + (size_t)row * (NL * HD) + c4) = o;
}

// --------------------- mean pool over sorted batch ids ---------------------
__device__ __forceinline__ int lbound(const int* __restrict__ b, int val) {
  int lo = 0, hi = NN;
  while (lo < hi) { int m = (lo + hi) >> 1; if (b[m] < val) lo = m + 1; else hi = m; }
  return lo;
}

__global__ __launch_bounds__(384) void pool_kernel(const int* __restrict__ batch,
    const float* __restrict__ feat, float* __restrict__ pooled) {
  int g = blockIdx.x;
  int lo = lbound(batch, g), hi = lbound(batch, g + 1);
  float s = 0.f;
  for (int r = lo; r < hi; ++r) s += feat[(size_t)r * (NL * HD) + threadIdx.x];
  float inv = 1.f / (float)max(hi - lo, 1);
  pooled[(size_t)g * (NL * HD) + threadIdx.x] = s * inv;
}

// ------------------------------- final MLP --------------------------------
__global__ __launch_bounds__(128) void mlp_kernel(const float* __restrict__ pooled,
    const float* __restrict__ W1, const float* __restrict__ b1,
    const float* __restrict__ W2, const float* __restrict__ b2,
    float* __restrict__ out) {
  int g = blockIdx.x, c = threadIdx.x;
  const float* p = pooled + (size_t)g * (NL * HD);
  float acc = b1[c];
  #pragma unroll 4
  for (int k = 0; k < NL * HD; ++k) acc = fmaf(p[k], W1[(size_t)k * HD + c], acc);
  acc = fmaxf(acc, 0.f);
  float prod = acc * W2[c];
  #pragma unroll
  for (int off = 32; off > 0; off >>= 1) prod += __shfl_xor(prod, off, 64);
  __shared__ float part[2];
  if ((c & 63) == 0) part[c >> 6] = prod;
  __syncthreads();
  if (c == 0) out[g] = part[0] + part[1] + b2[0];
}

// -------------------------------- launcher --------------------------------
extern "C" void kernel_launch(void* const* d_in, const int* in_sizes, int n_in,
                              void* d_out, int out_size, void* d_ws, size_t ws_size,
                              hipStream_t stream) {
  (void)in_sizes; (void)n_in; (void)out_size; (void)ws_size;
  const int*   z     = (const int*)d_in[0];
  const int*   ei    = (const int*)d_in[1];
  const int*   batch = (const int*)d_in[2];
  const float* ztab  = (const float*)d_in[3];
  const float* W1    = (const float*)d_in[4];
  const float* b1    = (const float*)d_in[5];
  const float* W2    = (const float*)d_in[6];
  const float* b2    = (const float*)d_in[7];
  const float* gamma = (const float*)d_in[8];
  const float* beta  = (const float*)d_in[9];
  const float* l1W   = (const float*)d_in[10];
  const float* l1b   = (const float*)d_in[11];
  const float* l2W   = (const float*)d_in[12];
  const float* l2b   = (const float*)d_in[13];
  float* out = (float*)d_out;

  char* w = (char*)d_ws;
  float* bufA   = (float*)w; w += (size_t)NN * HD * 4;
  float* bufB   = (float*)w; w += (size_t)NN * HD * 4;
  float* feat   = (float*)w; w += (size_t)NN * (NL * HD) * 4;
  float* pooled = (float*)w; w += (size_t)NG * (NL * HD) * 4;
  float* sums   = (float*)w; w += 256 * 4;
  float* sshift = (float*)w; w += 256 * 4;
  int*   rowptr = (int*)w;   w += (size_t)(NN + 1) * 4;
  int*   counts = (int*)w;   w += (size_t)NN * 4;
  int*   filloff= (int*)w;   w += (size_t)NN * 4;
  int*   esrc   = (int*)w;   w += (size_t)NE * 4;
  int*   bsums  = (int*)w;   w += (size_t)cdiv(NN, SCAN_CHUNK) * 4;

  const int* srcI = ei;
  const int* dstI = ei + NE;

  dim3 blk(256);
  const int g_nh = cdiv(NN * 32, 256);   // 12500
  const int g_nn = cdiv(NN, 256);
  const int g_ne = cdiv(NE, 256);
  const int nb_scan = cdiv(NN, SCAN_CHUNK);

  // ---- CSR build (graph is layer-invariant: build once per launch) ----
  zero_counts_kernel<<<g_nn, blk, 0, stream>>>(counts);
  hist_kernel<<<g_ne, blk, 0, stream>>>(dstI, counts);
  scan_block_kernel<<<nb_scan, blk, 0, stream>>>(counts, rowptr, bsums);
  scan_bsums_kernel<<<1, 64, 0, stream>>>(bsums, nb_scan);
  scan_add_kernel<<<g_nn, blk, 0, stream>>>(rowptr, bsums, filloff);
  fill_kernel<<<g_ne, blk, 0, stream>>>(srcI, dstI, filloff, esrc);

  embed_kernel<<<g_nh, blk, 0, stream>>>(z, ztab, bufA);

  for (int l = 0; l < NL; ++l) {
    const float* xin;
    int xstride;
    if (l == 0) { xin = bufA; xstride = HD; }
    else        { xin = feat + (l - 1) * HD; xstride = NL * HD; }
    float* aggbuf = (l & 1) ? bufA : bufB;   // l=0: B, l=1: A, l=2: B
    float* tmpbuf = (l & 1) ? bufB : bufA;

    agg_kernel<<<cdiv(NN, 4), blk, 0, stream>>>(rowptr, esrc, xin, xstride, aggbuf);
    gemm_relu_kernel<<<cdiv(NN, 64), blk, 0, stream>>>(aggbuf, W1 + (size_t)l * HD * HD,
                                                       b1 + l * HD, tmpbuf, NN);
    gemm_relu_kernel<<<cdiv(NN, 64), blk, 0, stream>>>(tmpbuf, W2 + (size_t)l * HD * HD,
                                                       b2 + l * HD, aggbuf, NN);
    zero_kernel<<<1, 256, 0, stream>>>(sums);
    bn_stats_kernel<<<512, blk, 0, stream>>>(aggbuf, sums);
    bn_finalize_kernel<<<1, 128, 0, stream>>>(sums, gamma + l * HD, beta + l * HD, sshift);
    bn_apply_kernel<<<g_nh, blk, 0, stream>>>(aggbuf, sshift, feat + l * HD);
  }

  pool_kernel<<<NG, 384, 0, stream>>>(batch, feat, pooled);
  mlp_kernel<<<NG, 128, 0, stream>>>(pooled, l1W, l1b, l2W, l2b, out);
}

// Round 9
// 1284.609 us; speedup vs baseline: 3.6305x; 1.0886x over previous
//
#include <hip/hip_runtime.h>

#define NN 100000
#define NE 1600000
#define HD 128
#define NL 3
#define NG 1024
#define BN_EPS 1e-5f
#define SCAN_CHUNK 1024

static inline int cdiv(int a, int b) { return (a + b - 1) / b; }

// ---------------- embedding gather: x[i,:] = table[z[i],:] ----------------
__global__ __launch_bounds__(256) void embed_kernel(const int* __restrict__ z,
    const float* __restrict__ table, float* __restrict__ x) {
  int t = blockIdx.x * 256 + threadIdx.x;            // over NN*32 float4s
  if (t >= NN * 32) return;
  int row = t >> 5, c4 = (t & 31) << 2;
  int zi = z[row];
  *(float4*)(x + (size_t)row * HD + c4) =
      *(const float4*)(table + (size_t)zi * HD + c4);
}

// --------------------------- CSR build pipeline ---------------------------
__global__ __launch_bounds__(256) void zero_counts_kernel(int* __restrict__ cnt) {
  int t = blockIdx.x * 256 + threadIdx.x;
  if (t < NN) cnt[t] = 0;
}

__global__ __launch_bounds__(256) void hist_kernel(const int* __restrict__ dstI,
    int* __restrict__ cnt) {
  int e = blockIdx.x * 256 + threadIdx.x;
  if (e < NE) atomicAdd(&cnt[dstI[e]], 1);
}

// block-local exclusive scan of SCAN_CHUNK elements; bsums gets chunk total
__global__ __launch_bounds__(256) void scan_block_kernel(const int* __restrict__ cnt,
    int* __restrict__ rowptr, int* __restrict__ bsums) {
  __shared__ int sh[SCAN_CHUNK];
  __shared__ int ts[256];
  int base = blockIdx.x * SCAN_CHUNK;
  for (int i = threadIdx.x; i < SCAN_CHUNK; i += 256)
    sh[i] = (base + i < NN) ? cnt[base + i] : 0;
  __syncthreads();
  int t4 = threadIdx.x * 4;
  int a0 = sh[t4], a1 = sh[t4 + 1], a2 = sh[t4 + 2], a3 = sh[t4 + 3];
  int tsum = a0 + a1 + a2 + a3;
  ts[threadIdx.x] = tsum;
  __syncthreads();
  for (int off = 1; off < 256; off <<= 1) {
    int v = ts[threadIdx.x];
    int u = (threadIdx.x >= off) ? ts[threadIdx.x - off] : 0;
    __syncthreads();
    ts[threadIdx.x] = v + u;
    __syncthreads();
  }
  int texcl = ts[threadIdx.x] - tsum;
  sh[t4] = texcl;
  sh[t4 + 1] = texcl + a0;
  sh[t4 + 2] = texcl + a0 + a1;
  sh[t4 + 3] = texcl + a0 + a1 + a2;
  __syncthreads();
  for (int i = threadIdx.x; i < SCAN_CHUNK; i += 256) {
    int g = base + i;
    if (g < NN) rowptr[g] = sh[i];
  }
  if (threadIdx.x == 255) bsums[blockIdx.x] = ts[255];
}

__global__ void scan_bsums_kernel(int* __restrict__ bsums, int nb) {
  if (threadIdx.x == 0) {
    int run = 0;
    for (int i = 0; i < nb; ++i) { int v = bsums[i]; bsums[i] = run; run += v; }
  }
}

__global__ __launch_bounds__(256) void scan_add_kernel(int* __restrict__ rowptr,
    const int* __restrict__ bsums, int* __restrict__ fill_off) {
  int t = blockIdx.x * 256 + threadIdx.x;
  if (t < NN) {
    int v = rowptr[t] + bsums[t / SCAN_CHUNK];
    rowptr[t] = v;
    fill_off[t] = v;
  }
  if (t == 0) rowptr[NN] = NE;
}

__global__ __launch_bounds__(256) void fill_kernel(const int* __restrict__ srcI,
    const int* __restrict__ dstI, int* __restrict__ fill_off, int* __restrict__ esrc) {
  int e = blockIdx.x * 256 + threadIdx.x;
  if (e >= NE) return;
  int d = dstI[e];
  int pos = atomicAdd(&fill_off[d], 1);
  esrc[pos] = srcI[e];
}

// ------- CSR gather aggregation: agg[n] = x[n] + sum_{s in N(n)} x[s] -------
// One wave per node. Edge indices are staged 64-at-a-time with one coalesced
// load and shuffle-broadcast; row gathers issued 4 deep to break the
// index->row dependent chain.
__global__ __launch_bounds__(256) void agg_kernel(const int* __restrict__ rowptr,
    const int* __restrict__ esrc, const float* __restrict__ xin, int xstride,
    float* __restrict__ agg) {
  int n = blockIdx.x * 4 + (threadIdx.x >> 6);       // one wave per node
  if (n >= NN) return;
  int lane = threadIdx.x & 63;
  int lo = rowptr[n], hi = rowptr[n + 1];
  int deg = hi - lo;
  float2 acc = *(const float2*)(xin + (size_t)n * xstride + lane * 2);  // self

  for (int base = 0; base < deg; base += 64) {
    int cnt = deg - base; if (cnt > 64) cnt = 64;
    int idx = (base + lane < deg) ? esrc[lo + base + lane] : 0;
    int j = 0;
    for (; j + 4 <= cnt; j += 4) {
      int s0 = __shfl(idx, j, 64);
      int s1 = __shfl(idx, j + 1, 64);
      int s2 = __shfl(idx, j + 2, 64);
      int s3 = __shfl(idx, j + 3, 64);
      float2 v0 = *(const float2*)(xin + (size_t)s0 * xstride + lane * 2);
      float2 v1 = *(const float2*)(xin + (size_t)s1 * xstride + lane * 2);
      float2 v2 = *(const float2*)(xin + (size_t)s2 * xstride + lane * 2);
      float2 v3 = *(const float2*)(xin + (size_t)s3 * xstride + lane * 2);
      acc.x += v0.x + v1.x + v2.x + v3.x;
      acc.y += v0.y + v1.y + v2.y + v3.y;
    }
    for (; j < cnt; ++j) {
      int s = __shfl(idx, j, 64);
      float2 v = *(const float2*)(xin + (size_t)s * xstride + lane * 2);
      acc.x += v.x; acc.y += v.y;
    }
  }
  *(float2*)(agg + (size_t)n * HD + lane * 2) = acc;
}

// ------------- C = relu(A @ B + bias), A:[M][128], B:[128][128] ------------
// STATS=1 additionally accumulates per-column sum / sum-of-squares of the
// written (post-relu) values into gsums[0..127] / gsums[128..255] (atomics).
template <int STATS>
__global__ __launch_bounds__(256) void gemm_relu_kernel_t(
    const float* __restrict__ A, const float* __restrict__ B,
    const float* __restrict__ bias, float* __restrict__ C, int M,
    float* __restrict__ gsums) {
  __shared__ float As[128][65];   // k-major (transposed), +1 pad
  __shared__ float Bs[32][128];   // one K-chunk of B
  __shared__ float csum[256];     // [0..127] sum, [128..255] sumsq (STATS)
  const int tid = threadIdx.x;
  const int row0 = blockIdx.x * 64;

  if (STATS) { csum[tid] = 0.f; }

  #pragma unroll
  for (int i = 0; i < 8; ++i) {
    int f = tid + i * 256;
    int row = f >> 5;
    int kq = (f & 31) << 2;
    int gr = row0 + row;
    float4 v = make_float4(0.f, 0.f, 0.f, 0.f);
    if (gr < M) v = *(const float4*)(A + (size_t)gr * HD + kq);
    As[kq + 0][row] = v.x; As[kq + 1][row] = v.y;
    As[kq + 2][row] = v.z; As[kq + 3][row] = v.w;
  }

  const int colbase = (tid & 15) << 2;
  const int rowbase = (tid >> 4) << 2;
  float acc[4][8] = {};

  for (int kc = 0; kc < 4; ++kc) {
    __syncthreads();
    #pragma unroll
    for (int i = 0; i < 4; ++i) {
      int f = tid + i * 256;
      int k = f >> 5;
      int c4 = (f & 31) << 2;
      *(float4*)(&Bs[k][c4]) = *(const float4*)(B + (size_t)(kc * 32 + k) * HD + c4);
    }
    __syncthreads();
    #pragma unroll
    for (int k = 0; k < 32; ++k) {
      const int kk = kc * 32 + k;
      float a0 = As[kk][rowbase + 0];
      float a1 = As[kk][rowbase + 1];
      float a2 = As[kk][rowbase + 2];
      float a3 = As[kk][rowbase + 3];
      float4 bl = *(const float4*)(&Bs[k][colbase]);
      float4 bh = *(const float4*)(&Bs[k][colbase + 64]);
      acc[0][0] += a0 * bl.x; acc[0][1] += a0 * bl.y; acc[0][2] += a0 * bl.z; acc[0][3] += a0 * bl.w;
      acc[0][4] += a0 * bh.x; acc[0][5] += a0 * bh.y; acc[0][6] += a0 * bh.z; acc[0][7] += a0 * bh.w;
      acc[1][0] += a1 * bl.x; acc[1][1] += a1 * bl.y; acc[1][2] += a1 * bl.z; acc[1][3] += a1 * bl.w;
      acc[1][4] += a1 * bh.x; acc[1][5] += a1 * bh.y; acc[1][6] += a1 * bh.z; acc[1][7] += a1 * bh.w;
      acc[2][0] += a2 * bl.x; acc[2][1] += a2 * bl.y; acc[2][2] += a2 * bl.z; acc[2][3] += a2 * bl.w;
      acc[2][4] += a2 * bh.x; acc[2][5] += a2 * bh.y; acc[2][6] += a2 * bh.z; acc[2][7] += a2 * bh.w;
      acc[3][0] += a3 * bl.x; acc[3][1] += a3 * bl.y; acc[3][2] += a3 * bl.z; acc[3][3] += a3 * bl.w;
      acc[3][4] += a3 * bh.x; acc[3][5] += a3 * bh.y; acc[3][6] += a3 * bh.z; acc[3][7] += a3 * bh.w;
    }
  }

  float4 bvl = *(const float4*)(bias + colbase);
  float4 bvh = *(const float4*)(bias + colbase + 64);
  float ps[8] = {}, pq[8] = {};
  #pragma unroll
  for (int r = 0; r < 4; ++r) {
    int gr = row0 + rowbase + r;
    if (gr < M) {
      float4 o;
      o.x = fmaxf(acc[r][0] + bvl.x, 0.f);
      o.y = fmaxf(acc[r][1] + bvl.y, 0.f);
      o.z = fmaxf(acc[r][2] + bvl.z, 0.f);
      o.w = fmaxf(acc[r][3] + bvl.w, 0.f);
      *(float4*)(C + (size_t)gr * HD + colbase) = o;
      if (STATS) {
        ps[0] += o.x; ps[1] += o.y; ps[2] += o.z; ps[3] += o.w;
        pq[0] += o.x * o.x; pq[1] += o.y * o.y; pq[2] += o.z * o.z; pq[3] += o.w * o.w;
      }
      o.x = fmaxf(acc[r][4] + bvh.x, 0.f);
      o.y = fmaxf(acc[r][5] + bvh.y, 0.f);
      o.z = fmaxf(acc[r][6] + bvh.z, 0.f);
      o.w = fmaxf(acc[r][7] + bvh.w, 0.f);
      *(float4*)(C + (size_t)gr * HD + colbase + 64) = o;
      if (STATS) {
        ps[4] += o.x; ps[5] += o.y; ps[6] += o.z; ps[7] += o.w;
        pq[4] += o.x * o.x; pq[5] += o.y * o.y; pq[6] += o.z * o.z; pq[7] += o.w * o.w;
      }
    }
  }

  if (STATS) {
    __syncthreads();   // csum zero-init complete (and tile work done)
    #pragma unroll
    for (int c = 0; c < 4; ++c) {
      atomicAdd(&csum[colbase + c], ps[c]);
      atomicAdd(&csum[128 + colbase + c], pq[c]);
      atomicAdd(&csum[colbase + 64 + c], ps[4 + c]);
      atomicAdd(&csum[128 + colbase + 64 + c], pq[4 + c]);
    }
    __syncthreads();
    if (tid < 128) {
      atomicAdd(&gsums[tid], csum[tid]);
      atomicAdd(&gsums[HD + tid], csum[128 + tid]);
    }
  }
}

// ----------------------------- BN finalize/apply ---------------------------
__global__ void zero_kernel(float* p) { p[threadIdx.x] = 0.f; }

__global__ void bn_finalize_kernel(const float* __restrict__ sums,
    const float* __restrict__ gamma, const float* __restrict__ beta,
    float* __restrict__ ss) {
  int c = threadIdx.x;                   // 128 threads
  float mu = sums[c] * (1.f / NN);
  float var = sums[HD + c] * (1.f / NN) - mu * mu;
  float sc = gamma[c] * rsqrtf(var + BN_EPS);
  ss[c] = sc;
  ss[HD + c] = beta[c] - mu * sc;
}

__global__ __launch_bounds__(256) void bn_apply_kernel(const float* __restrict__ h,
    const float* __restrict__ ss, float* __restrict__ featl) {
  int t = blockIdx.x * 256 + threadIdx.x;
  if (t >= NN * 32) return;
  int row = t >> 5, c4 = (t & 31) << 2;
  float4 v = *(const float4*)(h + (size_t)row * HD + c4);
  float4 sc = *(const float4*)(ss + c4);
  float4 sh = *(const float4*)(ss + HD + c4);
  float4 o;
  o.x = v.x * sc.x + sh.x;
  o.y = v.y * sc.y + sh.y;
  o.z = v.z * sc.z + sh.z;
  o.w = v.w * sc.w + sh.w;
  *(float4*)(featl + (size_t)row * (NL * HD) + c4) = o;
}

// --------------------- mean pool over sorted batch ids ---------------------
__device__ __forceinline__ int lbound(const int* __restrict__ b, int val) {
  int lo = 0, hi = NN;
  while (lo < hi) { int m = (lo + hi) >> 1; if (b[m] < val) lo = m + 1; else hi = m; }
  return lo;
}

__global__ __launch_bounds__(384) void pool_kernel(const int* __restrict__ batch,
    const float* __restrict__ feat, float* __restrict__ pooled) {
  int g = blockIdx.x;
  int lo = lbound(batch, g), hi = lbound(batch, g + 1);
  float s = 0.f;
  for (int r = lo; r < hi; ++r) s += feat[(size_t)r * (NL * HD) + threadIdx.x];
  float inv = 1.f / (float)max(hi - lo, 1);
  pooled[(size_t)g * (NL * HD) + threadIdx.x] = s * inv;
}

// ------------------------------- final MLP --------------------------------
__global__ __launch_bounds__(128) void mlp_kernel(const float* __restrict__ pooled,
    const float* __restrict__ W1, const float* __restrict__ b1,
    const float* __restrict__ W2, const float* __restrict__ b2,
    float* __restrict__ out) {
  int g = blockIdx.x, c = threadIdx.x;
  const float* p = pooled + (size_t)g * (NL * HD);
  float acc = b1[c];
  #pragma unroll 4
  for (int k = 0; k < NL * HD; ++k) acc = fmaf(p[k], W1[(size_t)k * HD + c], acc);
  acc = fmaxf(acc, 0.f);
  float prod = acc * W2[c];
  #pragma unroll
  for (int off = 32; off > 0; off >>= 1) prod += __shfl_xor(prod, off, 64);
  __shared__ float part[2];
  if ((c & 63) == 0) part[c >> 6] = prod;
  __syncthreads();
  if (c == 0) out[g] = part[0] + part[1] + b2[0];
}

// -------------------------------- launcher --------------------------------
extern "C" void kernel_launch(void* const* d_in, const int* in_sizes, int n_in,
                              void* d_out, int out_size, void* d_ws, size_t ws_size,
                              hipStream_t stream) {
  (void)in_sizes; (void)n_in; (void)out_size; (void)ws_size;
  const int*   z     = (const int*)d_in[0];
  const int*   ei    = (const int*)d_in[1];
  const int*   batch = (const int*)d_in[2];
  const float* ztab  = (const float*)d_in[3];
  const float* W1    = (const float*)d_in[4];
  const float* b1    = (const float*)d_in[5];
  const float* W2    = (const float*)d_in[6];
  const float* b2    = (const float*)d_in[7];
  const float* gamma = (const float*)d_in[8];
  const float* beta  = (const float*)d_in[9];
  const float* l1W   = (const float*)d_in[10];
  const float* l1b   = (const float*)d_in[11];
  const float* l2W   = (const float*)d_in[12];
  const float* l2b   = (const float*)d_in[13];
  float* out = (float*)d_out;

  char* w = (char*)d_ws;
  float* bufA   = (float*)w; w += (size_t)NN * HD * 4;
  float* bufB   = (float*)w; w += (size_t)NN * HD * 4;
  float* feat   = (float*)w; w += (size_t)NN * (NL * HD) * 4;
  float* pooled = (float*)w; w += (size_t)NG * (NL * HD) * 4;
  float* sums   = (float*)w; w += 256 * 4;
  float* sshift = (float*)w; w += 256 * 4;
  int*   rowptr = (int*)w;   w += (size_t)(NN + 1) * 4;
  int*   counts = (int*)w;   w += (size_t)NN * 4;
  int*   filloff= (int*)w;   w += (size_t)NN * 4;
  int*   esrc   = (int*)w;   w += (size_t)NE * 4;
  int*   bsums  = (int*)w;   w += (size_t)cdiv(NN, SCAN_CHUNK) * 4;

  const int* srcI = ei;
  const int* dstI = ei + NE;

  dim3 blk(256);
  const int g_nh = cdiv(NN * 32, 256);   // 12500
  const int g_nn = cdiv(NN, 256);
  const int g_ne = cdiv(NE, 256);
  const int nb_scan = cdiv(NN, SCAN_CHUNK);

  // ---- CSR build (graph is layer-invariant: build once per launch) ----
  zero_counts_kernel<<<g_nn, blk, 0, stream>>>(counts);
  hist_kernel<<<g_ne, blk, 0, stream>>>(dstI, counts);
  scan_block_kernel<<<nb_scan, blk, 0, stream>>>(counts, rowptr, bsums);
  scan_bsums_kernel<<<1, 64, 0, stream>>>(bsums, nb_scan);
  scan_add_kernel<<<g_nn, blk, 0, stream>>>(rowptr, bsums, filloff);
  fill_kernel<<<g_ne, blk, 0, stream>>>(srcI, dstI, filloff, esrc);

  embed_kernel<<<g_nh, blk, 0, stream>>>(z, ztab, bufA);

  for (int l = 0; l < NL; ++l) {
    const float* xin;
    int xstride;
    if (l == 0) { xin = bufA; xstride = HD; }
    else        { xin = feat + (l - 1) * HD; xstride = NL * HD; }
    float* aggbuf = (l & 1) ? bufA : bufB;   // l=0: B, l=1: A, l=2: B
    float* tmpbuf = (l & 1) ? bufB : bufA;

    agg_kernel<<<cdiv(NN, 4), blk, 0, stream>>>(rowptr, esrc, xin, xstride, aggbuf);
    gemm_relu_kernel_t<0><<<cdiv(NN, 64), blk, 0, stream>>>(aggbuf,
        W1 + (size_t)l * HD * HD, b1 + l * HD, tmpbuf, NN, nullptr);
    zero_kernel<<<1, 256, 0, stream>>>(sums);
    gemm_relu_kernel_t<1><<<cdiv(NN, 64), blk, 0, stream>>>(tmpbuf,
        W2 + (size_t)l * HD * HD, b2 + l * HD, aggbuf, NN, sums);
    bn_finalize_kernel<<<1, 128, 0, stream>>>(sums, gamma + l * HD, beta + l * HD, sshift);
    bn_apply_kernel<<<g_nh, blk, 0, stream>>>(aggbuf, sshift, feat + l * HD);
  }

  pool_kernel<<<NG, 384, 0, stream>>>(batch, feat, pooled);
  mlp_kernel<<<NG, 128, 0, stream>>>(pooled, l1W, l1b, l2W, l2b, out);
}

// Round 12
// 1199.896 us; speedup vs baseline: 3.8869x; 1.0706x over previous
//
#include <hip/hip_runtime.h>

#define NN 100000
#define NE 1600000
#define HD 128
#define NL 3
#define NG 1024
#define BN_EPS 1e-5f
#define SCAN_CHUNK 1024

static inline int cdiv(int a, int b) { return (a + b - 1) / b; }

// --------------------------- CSR build pipeline ---------------------------
__global__ __launch_bounds__(256) void zero_counts_kernel(int* __restrict__ cnt) {
  int t = blockIdx.x * 256 + threadIdx.x;
  if (t < NN) cnt[t] = 0;
}

__global__ __launch_bounds__(256) void hist_kernel(const int* __restrict__ dstI,
    int* __restrict__ cnt) {
  int e = blockIdx.x * 256 + threadIdx.x;
  if (e < NE) atomicAdd(&cnt[dstI[e]], 1);
}

// block-local exclusive scan of SCAN_CHUNK elements; bsums gets chunk total
__global__ __launch_bounds__(256) void scan_block_kernel(const int* __restrict__ cnt,
    int* __restrict__ rowptr, int* __restrict__ bsums) {
  __shared__ int sh[SCAN_CHUNK];
  __shared__ int ts[256];
  int base = blockIdx.x * SCAN_CHUNK;
  for (int i = threadIdx.x; i < SCAN_CHUNK; i += 256)
    sh[i] = (base + i < NN) ? cnt[base + i] : 0;
  __syncthreads();
  int t4 = threadIdx.x * 4;
  int a0 = sh[t4], a1 = sh[t4 + 1], a2 = sh[t4 + 2], a3 = sh[t4 + 3];
  int tsum = a0 + a1 + a2 + a3;
  ts[threadIdx.x] = tsum;
  __syncthreads();
  for (int off = 1; off < 256; off <<= 1) {
    int v = ts[threadIdx.x];
    int u = (threadIdx.x >= off) ? ts[threadIdx.x - off] : 0;
    __syncthreads();
    ts[threadIdx.x] = v + u;
    __syncthreads();
  }
  int texcl = ts[threadIdx.x] - tsum;
  sh[t4] = texcl;
  sh[t4 + 1] = texcl + a0;
  sh[t4 + 2] = texcl + a0 + a1;
  sh[t4 + 3] = texcl + a0 + a1 + a2;
  __syncthreads();
  for (int i = threadIdx.x; i < SCAN_CHUNK; i += 256) {
    int g = base + i;
    if (g < NN) rowptr[g] = sh[i];
  }
  if (threadIdx.x == 255) bsums[blockIdx.x] = ts[255];
}

__global__ void scan_bsums_kernel(int* __restrict__ bsums, int nb) {
  if (threadIdx.x == 0) {
    int run = 0;
    for (int i = 0; i < nb; ++i) { int v = bsums[i]; bsums[i] = run; run += v; }
  }
}

__global__ __launch_bounds__(256) void scan_add_kernel(int* __restrict__ rowptr,
    const int* __restrict__ bsums, int* __restrict__ fill_off) {
  int t = blockIdx.x * 256 + threadIdx.x;
  if (t < NN) {
    int v = rowptr[t] + bsums[t / SCAN_CHUNK];
    rowptr[t] = v;
    fill_off[t] = v;
  }
  if (t == 0) rowptr[NN] = NE;
}

// also records z[src] per edge so layer-0 can gather from the small z-table
__global__ __launch_bounds__(256) void fill_kernel(const int* __restrict__ srcI,
    const int* __restrict__ dstI, const int* __restrict__ z,
    int* __restrict__ fill_off, int* __restrict__ esrc, int* __restrict__ esrcz) {
  int e = blockIdx.x * 256 + threadIdx.x;
  if (e >= NE) return;
  int s = srcI[e];
  int d = dstI[e];
  int pos = atomicAdd(&fill_off[d], 1);
  esrc[pos] = s;
  esrcz[pos] = z[s];
}

// ------- CSR gather aggregation: agg[n] = self + sum_{s in N(n)} row[s] -----
// One wave per node, float2 per lane, 4-deep gather ILP (round-8-proven
// summation order). selfz!=nullptr (layer 0): rows come from the L2-resident
// z_table via esrcz, self row = table[z[n]] (bit-identical to embed+gather).
__global__ __launch_bounds__(256) void agg_kernel(const int* __restrict__ rowptr,
    const int* __restrict__ eidx, const float* __restrict__ xsrc, int xstride,
    const int* __restrict__ selfz, float* __restrict__ agg) {
  int n = blockIdx.x * 4 + (threadIdx.x >> 6);       // one wave per node
  if (n >= NN) return;
  int lane = threadIdx.x & 63;
  int lo = rowptr[n], hi = rowptr[n + 1];
  int deg = hi - lo;
  int selfrow = selfz ? selfz[n] : n;
  float2 acc = *(const float2*)(xsrc + (size_t)selfrow * xstride + lane * 2);

  for (int base = 0; base < deg; base += 64) {
    int cnt = deg - base; if (cnt > 64) cnt = 64;
    int idx = (base + lane < deg) ? eidx[lo + base + lane] : 0;
    int j = 0;
    for (; j + 4 <= cnt; j += 4) {
      int s0 = __shfl(idx, j, 64);
      int s1 = __shfl(idx, j + 1, 64);
      int s2 = __shfl(idx, j + 2, 64);
      int s3 = __shfl(idx, j + 3, 64);
      float2 v0 = *(const float2*)(xsrc + (size_t)s0 * xstride + lane * 2);
      float2 v1 = *(const float2*)(xsrc + (size_t)s1 * xstride + lane * 2);
      float2 v2 = *(const float2*)(xsrc + (size_t)s2 * xstride + lane * 2);
      float2 v3 = *(const float2*)(xsrc + (size_t)s3 * xstride + lane * 2);
      acc.x += v0.x + v1.x + v2.x + v3.x;
      acc.y += v0.y + v1.y + v2.y + v3.y;
    }
    for (; j < cnt; ++j) {
      int s = __shfl(idx, j, 64);
      float2 v = *(const float2*)(xsrc + (size_t)s * xstride + lane * 2);
      acc.x += v.x; acc.y += v.y;
    }
  }
  *(float2*)(agg + (size_t)n * HD + lane * 2) = acc;
}

// ------------- C = relu(A @ B + bias), A:[M][128], B:[128][128] ------------
// STATS=1 additionally accumulates per-column sum / sum-of-squares of the
// written (post-relu) values into gsums[0..127] / gsums[128..255].
// Block partials are fp32 (64 rows, accurate); global accumulation is fp64
// atomics -> order-insensitive, no E[x^2]-mu^2 fp32 cancellation downstream.
template <int STATS>
__global__ __launch_bounds__(256) void gemm_relu_kernel_t(
    const float* __restrict__ A, const float* __restrict__ B,
    const float* __restrict__ bias, float* __restrict__ C, int M,
    double* __restrict__ gsums) {
  __shared__ float As[128][65];   // k-major (transposed), +1 pad
  __shared__ float Bs[32][128];   // one K-chunk of B
  __shared__ float csum[256];     // [0..127] sum, [128..255] sumsq (STATS)
  const int tid = threadIdx.x;
  const int row0 = blockIdx.x * 64;

  if (STATS) { csum[tid] = 0.f; }

  #pragma unroll
  for (int i = 0; i < 8; ++i) {
    int f = tid + i * 256;
    int row = f >> 5;
    int kq = (f & 31) << 2;
    int gr = row0 + row;
    float4 v = make_float4(0.f, 0.f, 0.f, 0.f);
    if (gr < M) v = *(const float4*)(A + (size_t)gr * HD + kq);
    As[kq + 0][row] = v.x; As[kq + 1][row] = v.y;
    As[kq + 2][row] = v.z; As[kq + 3][row] = v.w;
  }

  const int colbase = (tid & 15) << 2;
  const int rowbase = (tid >> 4) << 2;
  float acc[4][8] = {};

  for (int kc = 0; kc < 4; ++kc) {
    __syncthreads();
    #pragma unroll
    for (int i = 0; i < 4; ++i) {
      int f = tid + i * 256;
      int k = f >> 5;
      int c4 = (f & 31) << 2;
      *(float4*)(&Bs[k][c4]) = *(const float4*)(B + (size_t)(kc * 32 + k) * HD + c4);
    }
    __syncthreads();
    #pragma unroll
    for (int k = 0; k < 32; ++k) {
      const int kk = kc * 32 + k;
      float a0 = As[kk][rowbase + 0];
      float a1 = As[kk][rowbase + 1];
      float a2 = As[kk][rowbase + 2];
      float a3 = As[kk][rowbase + 3];
      float4 bl = *(const float4*)(&Bs[k][colbase]);
      float4 bh = *(const float4*)(&Bs[k][colbase + 64]);
      acc[0][0] += a0 * bl.x; acc[0][1] += a0 * bl.y; acc[0][2] += a0 * bl.z; acc[0][3] += a0 * bl.w;
      acc[0][4] += a0 * bh.x; acc[0][5] += a0 * bh.y; acc[0][6] += a0 * bh.z; acc[0][7] += a0 * bh.w;
      acc[1][0] += a1 * bl.x; acc[1][1] += a1 * bl.y; acc[1][2] += a1 * bl.z; acc[1][3] += a1 * bl.w;
      acc[1][4] += a1 * bh.x; acc[1][5] += a1 * bh.y; acc[1][6] += a1 * bh.z; acc[1][7] += a1 * bh.w;
      acc[2][0] += a2 * bl.x; acc[2][1] += a2 * bl.y; acc[2][2] += a2 * bl.z; acc[2][3] += a2 * bl.w;
      acc[2][4] += a2 * bh.x; acc[2][5] += a2 * bh.y; acc[2][6] += a2 * bh.z; acc[2][7] += a2 * bh.w;
      acc[3][0] += a3 * bl.x; acc[3][1] += a3 * bl.y; acc[3][2] += a3 * bl.z; acc[3][3] += a3 * bl.w;
      acc[3][4] += a3 * bh.x; acc[3][5] += a3 * bh.y; acc[3][6] += a3 * bh.z; acc[3][7] += a3 * bh.w;
    }
  }

  float4 bvl = *(const float4*)(bias + colbase);
  float4 bvh = *(const float4*)(bias + colbase + 64);
  float ps[8] = {}, pq[8] = {};
  #pragma unroll
  for (int r = 0; r < 4; ++r) {
    int gr = row0 + rowbase + r;
    if (gr < M) {
      float4 o;
      o.x = fmaxf(acc[r][0] + bvl.x, 0.f);
      o.y = fmaxf(acc[r][1] + bvl.y, 0.f);
      o.z = fmaxf(acc[r][2] + bvl.z, 0.f);
      o.w = fmaxf(acc[r][3] + bvl.w, 0.f);
      *(float4*)(C + (size_t)gr * HD + colbase) = o;
      if (STATS) {
        ps[0] += o.x; ps[1] += o.y; ps[2] += o.z; ps[3] += o.w;
        pq[0] += o.x * o.x; pq[1] += o.y * o.y; pq[2] += o.z * o.z; pq[3] += o.w * o.w;
      }
      o.x = fmaxf(acc[r][4] + bvh.x, 0.f);
      o.y = fmaxf(acc[r][5] + bvh.y, 0.f);
      o.z = fmaxf(acc[r][6] + bvh.z, 0.f);
      o.w = fmaxf(acc[r][7] + bvh.w, 0.f);
      *(float4*)(C + (size_t)gr * HD + colbase + 64) = o;
      if (STATS) {
        ps[4] += o.x; ps[5] += o.y; ps[6] += o.z; ps[7] += o.w;
        pq[4] += o.x * o.x; pq[5] += o.y * o.y; pq[6] += o.z * o.z; pq[7] += o.w * o.w;
      }
    }
  }

  if (STATS) {
    __syncthreads();   // csum zero-init complete (and tile work done)
    #pragma unroll
    for (int c = 0; c < 4; ++c) {
      atomicAdd(&csum[colbase + c], ps[c]);
      atomicAdd(&csum[128 + colbase + c], pq[c]);
      atomicAdd(&csum[colbase + 64 + c], ps[4 + c]);
      atomicAdd(&csum[128 + colbase + 64 + c], pq[4 + c]);
    }
    __syncthreads();
    if (tid < 128) {
      atomicAdd(&gsums[tid], (double)csum[tid]);
      atomicAdd(&gsums[HD + tid], (double)csum[128 + tid]);
    }
  }
}

// ----------------------------- BN finalize/apply ---------------------------
__global__ void zero_d_kernel(double* p) { p[threadIdx.x] = 0.0; }

__global__ void bn_finalize_kernel(const double* __restrict__ sums,
    const float* __restrict__ gamma, const float* __restrict__ beta,
    float* __restrict__ ss) {
  int c = threadIdx.x;                   // 128 threads
  double mu = sums[c] * (1.0 / NN);
  double var = sums[HD + c] * (1.0 / NN) - mu * mu;
  float sc = gamma[c] * (float)(1.0 / sqrt(var + (double)BN_EPS));
  ss[c] = sc;
  ss[HD + c] = beta[c] - (float)mu * sc;
}

__global__ __launch_bounds__(256) void bn_apply_kernel(const float* __restrict__ h,
    const float* __restrict__ ss, float* __restrict__ featl) {
  int t = blockIdx.x * 256 + threadIdx.x;
  if (t >= NN * 32) return;
  int row = t >> 5, c4 = (t & 31) << 2;
  float4 v = *(const float4*)(h + (size_t)row * HD + c4);
  float4 sc = *(const float4*)(ss + c4);
  float4 sh = *(const float4*)(ss + HD + c4);
  float4 o;
  o.x = v.x * sc.x + sh.x;
  o.y = v.y * sc.y + sh.y;
  o.z = v.z * sc.z + sh.z;
  o.w = v.w * sc.w + sh.w;
  *(float4*)(featl + (size_t)row * (NL * HD) + c4) = o;
}

// --------------------- mean pool over sorted batch ids ---------------------
__device__ __forceinline__ int lbound(const int* __restrict__ b, int val) {
  int lo = 0, hi = NN;
  while (lo < hi) { int m = (lo + hi) >> 1; if (b[m] < val) lo = m + 1; else hi = m; }
  return lo;
}

__global__ __launch_bounds__(384) void pool_kernel(const int* __restrict__ batch,
    const float* __restrict__ feat, float* __restrict__ pooled) {
  int g = blockIdx.x;
  int lo = lbound(batch, g), hi = lbound(batch, g + 1);
  float s = 0.f;
  for (int r = lo; r < hi; ++r) s += feat[(size_t)r * (NL * HD) + threadIdx.x];
  float inv = 1.f / (float)max(hi - lo, 1);
  pooled[(size_t)g * (NL * HD) + threadIdx.x] = s * inv;
}

// ------------------------------- final MLP --------------------------------
__global__ __launch_bounds__(128) void mlp_kernel(const float* __restrict__ pooled,
    const float* __restrict__ W1, const float* __restrict__ b1,
    const float* __restrict__ W2, const float* __restrict__ b2,
    float* __restrict__ out) {
  int g = blockIdx.x, c = threadIdx.x;
  const float* p = pooled + (size_t)g * (NL * HD);
  float acc = b1[c];
  #pragma unroll 4
  for (int k = 0; k < NL * HD; ++k) acc = fmaf(p[k], W1[(size_t)k * HD + c], acc);
  acc = fmaxf(acc, 0.f);
  float prod = acc * W2[c];
  #pragma unroll
  for (int off = 32; off > 0; off >>= 1) prod += __shfl_xor(prod, off, 64);
  __shared__ float part[2];
  if ((c & 63) == 0) part[c >> 6] = prod;
  __syncthreads();
  if (c == 0) out[g] = part[0] + part[1] + b2[0];
}

// -------------------------------- launcher --------------------------------
extern "C" void kernel_launch(void* const* d_in, const int* in_sizes, int n_in,
                              void* d_out, int out_size, void* d_ws, size_t ws_size,
                              hipStream_t stream) {
  (void)in_sizes; (void)n_in; (void)out_size; (void)ws_size;
  const int*   z     = (const int*)d_in[0];
  const int*   ei    = (const int*)d_in[1];
  const int*   batch = (const int*)d_in[2];
  const float* ztab  = (const float*)d_in[3];
  const float* W1    = (const float*)d_in[4];
  const float* b1    = (const float*)d_in[5];
  const float* W2    = (const float*)d_in[6];
  const float* b2    = (const float*)d_in[7];
  const float* gamma = (const float*)d_in[8];
  const float* beta  = (const float*)d_in[9];
  const float* l1W   = (const float*)d_in[10];
  const float* l1b   = (const float*)d_in[11];
  const float* l2W   = (const float*)d_in[12];
  const float* l2b   = (const float*)d_in[13];
  float* out = (float*)d_out;

  char* w = (char*)d_ws;
  float*  bufA   = (float*)w;  w += (size_t)NN * HD * 4;
  float*  bufB   = (float*)w;  w += (size_t)NN * HD * 4;
  float*  feat   = (float*)w;  w += (size_t)NN * (NL * HD) * 4;
  float*  pooled = (float*)w;  w += (size_t)NG * (NL * HD) * 4;
  double* sums   = (double*)w; w += 256 * 8;
  float*  sshift = (float*)w;  w += 256 * 4;
  int*    rowptr = (int*)w;    w += (size_t)(NN + 1) * 4;
  int*    counts = (int*)w;    w += (size_t)NN * 4;
  int*    filloff= (int*)w;    w += (size_t)NN * 4;
  int*    esrc   = (int*)w;    w += (size_t)NE * 4;
  int*    bsums  = (int*)w;    w += (size_t)cdiv(NN, SCAN_CHUNK) * 4;
  // esrcz ALIASES bufA: written by fill_kernel, read only by layer-0 agg
  // (which writes bufB); bufA is first written later (GEMM1 output, l=0).
  // Keeps total workspace at the proven ~265 MB (a separate +6.4 MB buffer
  // overflowed the workspace in round 9 -> GPU fault).
  int* esrcz = (int*)bufA;

  const int* srcI = ei;
  const int* dstI = ei + NE;

  dim3 blk(256);
  const int g_nh = cdiv(NN * 32, 256);   // 12500
  const int g_nn = cdiv(NN, 256);
  const int g_ne = cdiv(NE, 256);
  const int nb_scan = cdiv(NN, SCAN_CHUNK);

  // ---- CSR build (graph is layer-invariant: build once per launch) ----
  zero_counts_kernel<<<g_nn, blk, 0, stream>>>(counts);
  hist_kernel<<<g_ne, blk, 0, stream>>>(dstI, counts);
  scan_block_kernel<<<nb_scan, blk, 0, stream>>>(counts, rowptr, bsums);
  scan_bsums_kernel<<<1, 64, 0, stream>>>(bsums, nb_scan);
  scan_add_kernel<<<g_nn, blk, 0, stream>>>(rowptr, bsums, filloff);
  fill_kernel<<<g_ne, blk, 0, stream>>>(srcI, dstI, z, filloff, esrc, esrcz);

  for (int l = 0; l < NL; ++l) {
    float* aggbuf = (l & 1) ? bufA : bufB;   // l=0: B, l=1: A, l=2: B
    float* tmpbuf = (l & 1) ? bufB : bufA;

    if (l == 0) {
      // gather straight from the 512 KB z-table (L2-resident)
      agg_kernel<<<cdiv(NN, 4), blk, 0, stream>>>(rowptr, esrcz, ztab, HD, z, aggbuf);
    } else {
      agg_kernel<<<cdiv(NN, 4), blk, 0, stream>>>(rowptr, esrc,
          feat + (l - 1) * HD, NL * HD, nullptr, aggbuf);
    }
    gemm_relu_kernel_t<0><<<cdiv(NN, 64), blk, 0, stream>>>(aggbuf,
        W1 + (size_t)l * HD * HD, b1 + l * HD, tmpbuf, NN, nullptr);
    zero_d_kernel<<<1, 256, 0, stream>>>(sums);
    gemm_relu_kernel_t<1><<<cdiv(NN, 64), blk, 0, stream>>>(tmpbuf,
        W2 + (size_t)l * HD * HD, b2 + l * HD, aggbuf, NN, sums);
    bn_finalize_kernel<<<1, 128, 0, stream>>>(sums, gamma + l * HD, beta + l * HD, sshift);
    bn_apply_kernel<<<g_nh, blk, 0, stream>>>(aggbuf, sshift, feat + l * HD);
  }

  pool_kernel<<<NG, 384, 0, stream>>>(batch, feat, pooled);
  mlp_kernel<<<NG, 128, 0, stream>>>(pooled, l1W, l1b, l2W, l2b, out);
}

// Round 13
// 1140.578 us; speedup vs baseline: 4.0890x; 1.0520x over previous
//
#include <hip/hip_runtime.h>

#define NN 100000
#define NE 1600000
#define HD 128
#define NL 3
#define NG 1024
#define BN_EPS 1e-5f
#define SCAN_CHUNK 1024

static inline int cdiv(int a, int b) { return (a + b - 1) / b; }

// --------------------------- CSR build pipeline ---------------------------
__global__ __launch_bounds__(256) void zero_counts_kernel(int* __restrict__ cnt) {
  int t = blockIdx.x * 256 + threadIdx.x;
  if (t < NN) cnt[t] = 0;
}

__global__ __launch_bounds__(256) void hist_kernel(const int* __restrict__ dstI,
    int* __restrict__ cnt) {
  int e = blockIdx.x * 256 + threadIdx.x;
  if (e < NE) atomicAdd(&cnt[dstI[e]], 1);
}

__global__ __launch_bounds__(256) void scan_block_kernel(const int* __restrict__ cnt,
    int* __restrict__ rowptr, int* __restrict__ bsums) {
  __shared__ int sh[SCAN_CHUNK];
  __shared__ int ts[256];
  int base = blockIdx.x * SCAN_CHUNK;
  for (int i = threadIdx.x; i < SCAN_CHUNK; i += 256)
    sh[i] = (base + i < NN) ? cnt[base + i] : 0;
  __syncthreads();
  int t4 = threadIdx.x * 4;
  int a0 = sh[t4], a1 = sh[t4 + 1], a2 = sh[t4 + 2], a3 = sh[t4 + 3];
  int tsum = a0 + a1 + a2 + a3;
  ts[threadIdx.x] = tsum;
  __syncthreads();
  for (int off = 1; off < 256; off <<= 1) {
    int v = ts[threadIdx.x];
    int u = (threadIdx.x >= off) ? ts[threadIdx.x - off] : 0;
    __syncthreads();
    ts[threadIdx.x] = v + u;
    __syncthreads();
  }
  int texcl = ts[threadIdx.x] - tsum;
  sh[t4] = texcl;
  sh[t4 + 1] = texcl + a0;
  sh[t4 + 2] = texcl + a0 + a1;
  sh[t4 + 3] = texcl + a0 + a1 + a2;
  __syncthreads();
  for (int i = threadIdx.x; i < SCAN_CHUNK; i += 256) {
    int g = base + i;
    if (g < NN) rowptr[g] = sh[i];
  }
  if (threadIdx.x == 255) bsums[blockIdx.x] = ts[255];
}

__global__ void scan_bsums_kernel(int* __restrict__ bsums, int nb) {
  if (threadIdx.x == 0) {
    int run = 0;
    for (int i = 0; i < nb; ++i) { int v = bsums[i]; bsums[i] = run; run += v; }
  }
}

__global__ __launch_bounds__(256) void scan_add_kernel(int* __restrict__ rowptr,
    const int* __restrict__ bsums, int* __restrict__ fill_off) {
  int t = blockIdx.x * 256 + threadIdx.x;
  if (t < NN) {
    int v = rowptr[t] + bsums[t / SCAN_CHUNK];
    rowptr[t] = v;
    fill_off[t] = v;
  }
  if (t == 0) rowptr[NN] = NE;
}

__global__ __launch_bounds__(256) void fill_kernel(const int* __restrict__ srcI,
    const int* __restrict__ dstI, const int* __restrict__ z,
    int* __restrict__ fill_off, int* __restrict__ esrc, int* __restrict__ esrcz) {
  int e = blockIdx.x * 256 + threadIdx.x;
  if (e >= NE) return;
  int s = srcI[e];
  int d = dstI[e];
  int pos = atomicAdd(&fill_off[d], 1);
  esrc[pos] = s;
  esrcz[pos] = z[s];
}

// ------- CSR gather aggregation + optional folded BN of the INPUT layer -----
// agg[n] = sc (.) (row[self] + sum_{s in N(n)} row[s]) + (deg+1) * sh
// ss==nullptr -> identity affine (layer 0). float2/lane, 4-deep gather ILP
// (round-8-proven order). selfz!=nullptr: layer-0 z-table mode.
__global__ __launch_bounds__(256) void agg_kernel(const int* __restrict__ rowptr,
    const int* __restrict__ eidx, const float* __restrict__ xsrc, int xstride,
    const int* __restrict__ selfz, const float* __restrict__ ss,
    float* __restrict__ agg) {
  int n = blockIdx.x * 4 + (threadIdx.x >> 6);       // one wave per node
  if (n >= NN) return;
  int lane = threadIdx.x & 63;
  int lo = rowptr[n], hi = rowptr[n + 1];
  int deg = hi - lo;
  int selfrow = selfz ? selfz[n] : n;
  float2 acc = *(const float2*)(xsrc + (size_t)selfrow * xstride + lane * 2);

  for (int base = 0; base < deg; base += 64) {
    int cnt = deg - base; if (cnt > 64) cnt = 64;
    int idx = (base + lane < deg) ? eidx[lo + base + lane] : 0;
    int j = 0;
    for (; j + 4 <= cnt; j += 4) {
      int s0 = __shfl(idx, j, 64);
      int s1 = __shfl(idx, j + 1, 64);
      int s2 = __shfl(idx, j + 2, 64);
      int s3 = __shfl(idx, j + 3, 64);
      float2 v0 = *(const float2*)(xsrc + (size_t)s0 * xstride + lane * 2);
      float2 v1 = *(const float2*)(xsrc + (size_t)s1 * xstride + lane * 2);
      float2 v2 = *(const float2*)(xsrc + (size_t)s2 * xstride + lane * 2);
      float2 v3 = *(const float2*)(xsrc + (size_t)s3 * xstride + lane * 2);
      acc.x += v0.x + v1.x + v2.x + v3.x;
      acc.y += v0.y + v1.y + v2.y + v3.y;
    }
    for (; j < cnt; ++j) {
      int s = __shfl(idx, j, 64);
      float2 v = *(const float2*)(xsrc + (size_t)s * xstride + lane * 2);
      acc.x += v.x; acc.y += v.y;
    }
  }

  float2 o = acc;
  if (ss) {
    float scx = ss[lane * 2], scy = ss[lane * 2 + 1];
    float shx = ss[128 + lane * 2], shy = ss[129 + lane * 2];
    float cntf = (float)(deg + 1);
    o.x = acc.x * scx + cntf * shx;
    o.y = acc.y * scy + cntf * shy;
  }
  *(float2*)(agg + (size_t)n * HD + lane * 2) = o;
}

// ---- C = relu(A @ B + bias); A:[M][128] (stride HD), B:[128][128],
// ---- C stride cstride. 128x128 tile, 8x8 acc/thread, float4 LDS reads.
// STATS=1: per-column sum/sumsq of written values -> gsums (fp64 atomics).
template <int STATS>
__global__ __launch_bounds__(256) void gemm128_kernel(
    const float* __restrict__ A, const float* __restrict__ B,
    const float* __restrict__ bias, float* __restrict__ C, int cstride, int M,
    double* __restrict__ gsums) {
  __shared__ float As[32][136];   // k-major; rows 16B-aligned (136*4=544B)
  __shared__ float Bs[32][136];
  __shared__ float csum[256];
  const int tid = threadIdx.x;
  const int row0 = blockIdx.x * 128;
  const int tr = tid >> 4;        // 0..15 -> rows tr*8..tr*8+7
  const int tc = tid & 15;        // 0..15 -> cols tc*8..tc*8+7

  if (STATS) csum[tid] = 0.f;

  float acc[8][8] = {};

  for (int kc = 0; kc < 4; ++kc) {
    __syncthreads();
    // stage A chunk: 128 rows x 32 k, transposed to k-major
    #pragma unroll
    for (int i = 0; i < 4; ++i) {
      int f = tid + i * 256;        // row = f>>3, kq = f&7
      int row = f >> 3, kq = f & 7;
      int gr = row0 + row;
      float4 v = make_float4(0.f, 0.f, 0.f, 0.f);
      if (gr < M) v = *(const float4*)(A + (size_t)gr * HD + kc * 32 + kq * 4);
      As[kq * 4 + 0][row] = v.x; As[kq * 4 + 1][row] = v.y;
      As[kq * 4 + 2][row] = v.z; As[kq * 4 + 3][row] = v.w;
    }
    // stage B chunk: 32 k x 128 cols
    #pragma unroll
    for (int i = 0; i < 4; ++i) {
      int f = tid + i * 256;        // k = f>>5, c4 = (f&31)*4
      int k = f >> 5, c4 = (f & 31) << 2;
      *(float4*)(&Bs[k][c4]) = *(const float4*)(B + (size_t)(kc * 32 + k) * HD + c4);
    }
    __syncthreads();
    #pragma unroll
    for (int k = 0; k < 32; ++k) {
      float4 a0 = *(const float4*)(&As[k][tr * 8]);
      float4 a1 = *(const float4*)(&As[k][tr * 8 + 4]);
      float4 b0 = *(const float4*)(&Bs[k][tc * 8]);
      float4 b1 = *(const float4*)(&Bs[k][tc * 8 + 4]);
      float av[8] = {a0.x, a0.y, a0.z, a0.w, a1.x, a1.y, a1.z, a1.w};
      float bv[8] = {b0.x, b0.y, b0.z, b0.w, b1.x, b1.y, b1.z, b1.w};
      #pragma unroll
      for (int r = 0; r < 8; ++r)
        #pragma unroll
        for (int c = 0; c < 8; ++c)
          acc[r][c] += av[r] * bv[c];
    }
  }

  float4 bv0 = *(const float4*)(bias + tc * 8);
  float4 bv1 = *(const float4*)(bias + tc * 8 + 4);
  float bb[8] = {bv0.x, bv0.y, bv0.z, bv0.w, bv1.x, bv1.y, bv1.z, bv1.w};
  float ps[8] = {}, pq[8] = {};
  #pragma unroll
  for (int r = 0; r < 8; ++r) {
    int gr = row0 + tr * 8 + r;
    if (gr < M) {
      float o[8];
      #pragma unroll
      for (int c = 0; c < 8; ++c) o[c] = fmaxf(acc[r][c] + bb[c], 0.f);
      *(float4*)(C + (size_t)gr * cstride + tc * 8)     = make_float4(o[0], o[1], o[2], o[3]);
      *(float4*)(C + (size_t)gr * cstride + tc * 8 + 4) = make_float4(o[4], o[5], o[6], o[7]);
      if (STATS) {
        #pragma unroll
        for (int c = 0; c < 8; ++c) { ps[c] += o[c]; pq[c] += o[c] * o[c]; }
      }
    }
  }

  if (STATS) {
    __syncthreads();
    #pragma unroll
    for (int c = 0; c < 8; ++c) {
      atomicAdd(&csum[tc * 8 + c], ps[c]);
      atomicAdd(&csum[128 + tc * 8 + c], pq[c]);
    }
    __syncthreads();
    if (tid < 128) {
      atomicAdd(&gsums[tid], (double)csum[tid]);
      atomicAdd(&gsums[HD + tid], (double)csum[128 + tid]);
    }
  }
}

// ----------------------------- BN finalize ---------------------------------
__global__ void zero_d_kernel(double* p) { p[threadIdx.x] = 0.0; }

__global__ void bn_finalize_kernel(const double* __restrict__ sums,
    const float* __restrict__ gamma, const float* __restrict__ beta,
    float* __restrict__ ss) {
  int c = threadIdx.x;                   // 128 threads
  double mu = sums[c] * (1.0 / NN);
  double var = sums[HD + c] * (1.0 / NN) - mu * mu;
  float sc = gamma[c] * (float)(1.0 / sqrt(var + (double)BN_EPS));
  ss[c] = sc;
  ss[HD + c] = beta[c] - (float)mu * sc;
}

// ---------- mean pool over sorted batch ids + per-layer BN affine ----------
__device__ __forceinline__ int lbound(const int* __restrict__ b, int val) {
  int lo = 0, hi = NN;
  while (lo < hi) { int m = (lo + hi) >> 1; if (b[m] < val) lo = m + 1; else hi = m; }
  return lo;
}

__global__ __launch_bounds__(384) void pool_kernel(const int* __restrict__ batch,
    const float* __restrict__ feat, const float* __restrict__ ssAll,
    float* __restrict__ pooled) {
  int g = blockIdx.x;
  int c = threadIdx.x;                   // 0..383
  int l = c >> 7, cc = c & 127;
  float sc = ssAll[l * 256 + cc], sh = ssAll[l * 256 + 128 + cc];
  int lo = lbound(batch, g), hi = lbound(batch, g + 1);
  float s = 0.f;
  for (int r = lo; r < hi; ++r) s += feat[(size_t)r * (NL * HD) + c];
  float inv = 1.f / (float)max(hi - lo, 1);
  pooled[(size_t)g * (NL * HD) + c] = sc * (s * inv) + sh;
}

// ------------------------------- final MLP --------------------------------
__global__ __launch_bounds__(128) void mlp_kernel(const float* __restrict__ pooled,
    const float* __restrict__ W1, const float* __restrict__ b1,
    const float* __restrict__ W2, const float* __restrict__ b2,
    float* __restrict__ out) {
  int g = blockIdx.x, c = threadIdx.x;
  const float* p = pooled + (size_t)g * (NL * HD);
  float acc = b1[c];
  #pragma unroll 4
  for (int k = 0; k < NL * HD; ++k) acc = fmaf(p[k], W1[(size_t)k * HD + c], acc);
  acc = fmaxf(acc, 0.f);
  float prod = acc * W2[c];
  #pragma unroll
  for (int off = 32; off > 0; off >>= 1) prod += __shfl_xor(prod, off, 64);
  __shared__ float part[2];
  if ((c & 63) == 0) part[c >> 6] = prod;
  __syncthreads();
  if (c == 0) out[g] = part[0] + part[1] + b2[0];
}

// -------------------------------- launcher --------------------------------
extern "C" void kernel_launch(void* const* d_in, const int* in_sizes, int n_in,
                              void* d_out, int out_size, void* d_ws, size_t ws_size,
                              hipStream_t stream) {
  (void)in_sizes; (void)n_in; (void)out_size; (void)ws_size;
  const int*   z     = (const int*)d_in[0];
  const int*   ei    = (const int*)d_in[1];
  const int*   batch = (const int*)d_in[2];
  const float* ztab  = (const float*)d_in[3];
  const float* W1    = (const float*)d_in[4];
  const float* b1    = (const float*)d_in[5];
  const float* W2    = (const float*)d_in[6];
  const float* b2    = (const float*)d_in[7];
  const float* gamma = (const float*)d_in[8];
  const float* beta  = (const float*)d_in[9];
  const float* l1W   = (const float*)d_in[10];
  const float* l1b   = (const float*)d_in[11];
  const float* l2W   = (const float*)d_in[12];
  const float* l2b   = (const float*)d_in[13];
  float* out = (float*)d_out;

  char* w = (char*)d_ws;
  float*  bufA   = (float*)w;  w += (size_t)NN * HD * 4;   // GEMM1 out
  float*  bufB   = (float*)w;  w += (size_t)NN * HD * 4;   // agg out
  float*  feat   = (float*)w;  w += (size_t)NN * (NL * HD) * 4; // pre-BN h, JK concat
  float*  pooled = (float*)w;  w += (size_t)NG * (NL * HD) * 4;
  double* sums   = (double*)w; w += 256 * 8;
  float*  ssAll  = (float*)w;  w += (size_t)NL * 256 * 4;  // per-layer BN affine
  int*    rowptr = (int*)w;    w += (size_t)(NN + 1) * 4;
  int*    counts = (int*)w;    w += (size_t)NN * 4;
  int*    filloff= (int*)w;    w += (size_t)NN * 4;
  int*    esrc   = (int*)w;    w += (size_t)NE * 4;
  int*    bsums  = (int*)w;    w += (size_t)cdiv(NN, SCAN_CHUNK) * 4;
  // esrcz ALIASES bufA: written by fill_kernel, read only by layer-0 agg
  // (which writes bufB); bufA is first written later (GEMM1 output, l=0).
  int* esrcz = (int*)bufA;

  const int* srcI = ei;
  const int* dstI = ei + NE;

  dim3 blk(256);
  const int g_nn = cdiv(NN, 256);
  const int g_ne = cdiv(NE, 256);
  const int nb_scan = cdiv(NN, SCAN_CHUNK);
  const int g_gemm = cdiv(NN, 128);      // 782

  // ---- CSR build (graph is layer-invariant: build once per launch) ----
  zero_counts_kernel<<<g_nn, blk, 0, stream>>>(counts);
  hist_kernel<<<g_ne, blk, 0, stream>>>(dstI, counts);
  scan_block_kernel<<<nb_scan, blk, 0, stream>>>(counts, rowptr, bsums);
  scan_bsums_kernel<<<1, 64, 0, stream>>>(bsums, nb_scan);
  scan_add_kernel<<<g_nn, blk, 0, stream>>>(rowptr, bsums, filloff);
  fill_kernel<<<g_ne, blk, 0, stream>>>(srcI, dstI, z, filloff, esrc, esrcz);

  for (int l = 0; l < NL; ++l) {
    if (l == 0) {
      // gather straight from the 512 KB z-table (L2-resident); no BN yet
      agg_kernel<<<cdiv(NN, 4), blk, 0, stream>>>(rowptr, esrcz, ztab, HD,
                                                  z, nullptr, bufB);
    } else {
      // gather pre-BN h of layer l-1 from feat; fold its BN affine here
      agg_kernel<<<cdiv(NN, 4), blk, 0, stream>>>(rowptr, esrc,
          feat + (l - 1) * HD, NL * HD, nullptr, ssAll + (l - 1) * 256, bufB);
    }
    gemm128_kernel<0><<<g_gemm, blk, 0, stream>>>(bufB,
        W1 + (size_t)l * HD * HD, b1 + l * HD, bufA, HD, NN, nullptr);
    zero_d_kernel<<<1, 256, 0, stream>>>(sums);
    // GEMM2 writes pre-BN h straight into its feat slice + column stats
    gemm128_kernel<1><<<g_gemm, blk, 0, stream>>>(bufA,
        W2 + (size_t)l * HD * HD, b2 + l * HD, feat + l * HD, NL * HD, NN, sums);
    bn_finalize_kernel<<<1, 128, 0, stream>>>(sums, gamma + l * HD,
                                              beta + l * HD, ssAll + l * 256);
  }

  pool_kernel<<<NG, 384, 0, stream>>>(batch, feat, ssAll, pooled);
  mlp_kernel<<<NG, 128, 0, stream>>>(pooled, l1W, l1b, l2W, l2b, out);
}

// Round 14
// 1062.404 us; speedup vs baseline: 4.3899x; 1.0736x over previous
//
#include <hip/hip_runtime.h>

#define NN 100000
#define NE 1600000
#define HD 128
#define NL 3
#define NG 1024
#define BN_EPS 1e-5f
#define SCAN_CHUNK 1024

static inline int cdiv(int a, int b) { return (a + b - 1) / b; }

typedef __attribute__((ext_vector_type(8))) short short8v;
typedef __attribute__((ext_vector_type(4))) float f32x4;

// bf16 round-to-nearest-even split helpers (finite values only)
static __device__ __forceinline__ unsigned short f2bf_rne(float x) {
  unsigned int u = __float_as_uint(x);
  unsigned int r = (u + 0x7FFFu + ((u >> 16) & 1u)) >> 16;
  return (unsigned short)r;
}
static __device__ __forceinline__ float bf2f(unsigned short s) {
  return __uint_as_float(((unsigned int)s) << 16);
}

// --------------------------- CSR build pipeline ---------------------------
__global__ __launch_bounds__(256) void zero_counts_kernel(int* __restrict__ cnt) {
  int t = blockIdx.x * 256 + threadIdx.x;
  if (t < NN) cnt[t] = 0;
}

__global__ __launch_bounds__(256) void hist_kernel(const int* __restrict__ dstI,
    int* __restrict__ cnt) {
  int e = blockIdx.x * 256 + threadIdx.x;
  if (e < NE) atomicAdd(&cnt[dstI[e]], 1);
}

__global__ __launch_bounds__(256) void scan_block_kernel(const int* __restrict__ cnt,
    int* __restrict__ rowptr, int* __restrict__ bsums) {
  __shared__ int sh[SCAN_CHUNK];
  __shared__ int ts[256];
  int base = blockIdx.x * SCAN_CHUNK;
  for (int i = threadIdx.x; i < SCAN_CHUNK; i += 256)
    sh[i] = (base + i < NN) ? cnt[base + i] : 0;
  __syncthreads();
  int t4 = threadIdx.x * 4;
  int a0 = sh[t4], a1 = sh[t4 + 1], a2 = sh[t4 + 2], a3 = sh[t4 + 3];
  int tsum = a0 + a1 + a2 + a3;
  ts[threadIdx.x] = tsum;
  __syncthreads();
  for (int off = 1; off < 256; off <<= 1) {
    int v = ts[threadIdx.x];
    int u = (threadIdx.x >= off) ? ts[threadIdx.x - off] : 0;
    __syncthreads();
    ts[threadIdx.x] = v + u;
    __syncthreads();
  }
  int texcl = ts[threadIdx.x] - tsum;
  sh[t4] = texcl;
  sh[t4 + 1] = texcl + a0;
  sh[t4 + 2] = texcl + a0 + a1;
  sh[t4 + 3] = texcl + a0 + a1 + a2;
  __syncthreads();
  for (int i = threadIdx.x; i < SCAN_CHUNK; i += 256) {
    int g = base + i;
    if (g < NN) rowptr[g] = sh[i];
  }
  if (threadIdx.x == 255) bsums[blockIdx.x] = ts[255];
}

__global__ void scan_bsums_kernel(int* __restrict__ bsums, int nb) {
  if (threadIdx.x == 0) {
    int run = 0;
    for (int i = 0; i < nb; ++i) { int v = bsums[i]; bsums[i] = run; run += v; }
  }
}

__global__ __launch_bounds__(256) void scan_add_kernel(int* __restrict__ rowptr,
    const int* __restrict__ bsums, int* __restrict__ fill_off) {
  int t = blockIdx.x * 256 + threadIdx.x;
  if (t < NN) {
    int v = rowptr[t] + bsums[t / SCAN_CHUNK];
    rowptr[t] = v;
    fill_off[t] = v;
  }
  if (t == 0) rowptr[NN] = NE;
}

__global__ __launch_bounds__(256) void fill_kernel(const int* __restrict__ srcI,
    const int* __restrict__ dstI, const int* __restrict__ z,
    int* __restrict__ fill_off, int* __restrict__ esrc, int* __restrict__ esrcz) {
  int e = blockIdx.x * 256 + threadIdx.x;
  if (e >= NE) return;
  int s = srcI[e];
  int d = dstI[e];
  int pos = atomicAdd(&fill_off[d], 1);
  esrc[pos] = s;
  esrcz[pos] = z[s];
}

// ------- CSR gather aggregation + optional folded BN of the INPUT layer -----
__global__ __launch_bounds__(256) void agg_kernel(const int* __restrict__ rowptr,
    const int* __restrict__ eidx, const float* __restrict__ xsrc, int xstride,
    const int* __restrict__ selfz, const float* __restrict__ ss,
    float* __restrict__ agg) {
  int n = blockIdx.x * 4 + (threadIdx.x >> 6);       // one wave per node
  if (n >= NN) return;
  int lane = threadIdx.x & 63;
  int lo = rowptr[n], hi = rowptr[n + 1];
  int deg = hi - lo;
  int selfrow = selfz ? selfz[n] : n;
  float2 acc = *(const float2*)(xsrc + (size_t)selfrow * xstride + lane * 2);

  for (int base = 0; base < deg; base += 64) {
    int cnt = deg - base; if (cnt > 64) cnt = 64;
    int idx = (base + lane < deg) ? eidx[lo + base + lane] : 0;
    int j = 0;
    for (; j + 4 <= cnt; j += 4) {
      int s0 = __shfl(idx, j, 64);
      int s1 = __shfl(idx, j + 1, 64);
      int s2 = __shfl(idx, j + 2, 64);
      int s3 = __shfl(idx, j + 3, 64);
      float2 v0 = *(const float2*)(xsrc + (size_t)s0 * xstride + lane * 2);
      float2 v1 = *(const float2*)(xsrc + (size_t)s1 * xstride + lane * 2);
      float2 v2 = *(const float2*)(xsrc + (size_t)s2 * xstride + lane * 2);
      float2 v3 = *(const float2*)(xsrc + (size_t)s3 * xstride + lane * 2);
      acc.x += v0.x + v1.x + v2.x + v3.x;
      acc.y += v0.y + v1.y + v2.y + v3.y;
    }
    for (; j < cnt; ++j) {
      int s = __shfl(idx, j, 64);
      float2 v = *(const float2*)(xsrc + (size_t)s * xstride + lane * 2);
      acc.x += v.x; acc.y += v.y;
    }
  }

  float2 o = acc;
  if (ss) {
    float scx = ss[lane * 2], scy = ss[lane * 2 + 1];
    float shx = ss[128 + lane * 2], shy = ss[129 + lane * 2];
    float cntf = (float)(deg + 1);
    o.x = acc.x * scx + cntf * shx;
    o.y = acc.y * scy + cntf * shy;
  }
  *(float2*)(agg + (size_t)n * HD + lane * 2) = o;
}

// ---- split weight matrix B[128][128] fp32 -> fragment-major bf16 hi/lo ----
// storage order [kc 0..3][ct 0..7][lane 0..63][j 0..7]; lane l supplies
// B[kc*32 + (l>>4)*8 + j][ct*16 + (l&15)]  (same (g,j)->k map as A frags)
__global__ __launch_bounds__(256) void bsplit_kernel(const float* __restrict__ B,
    short* __restrict__ bh, short* __restrict__ bl) {
  int t = blockIdx.x * 256 + threadIdx.x;   // 0..2047
  if (t >= 2048) return;
  int kc = t >> 9, ct = (t >> 6) & 7, l = t & 63;
  int kbase = kc * 32 + (l >> 4) * 8;
  int col = ct * 16 + (l & 15);
  short8v H, L;
  #pragma unroll
  for (int j = 0; j < 8; ++j) {
    float v = B[(size_t)(kbase + j) * HD + col];
    unsigned short h = f2bf_rne(v);
    float rem = v - bf2f(h);
    H[j] = (short)h;
    L[j] = (short)f2bf_rne(rem);
  }
  *(short8v*)(bh + (size_t)t * 8) = H;
  *(short8v*)(bl + (size_t)t * 8) = L;
}

// ---- C = relu(A @ B + bias) via split-bf16 MFMA; A:[M][HD] fp32, B given as
// ---- fragment-major hi/lo (bsplit_kernel). C stride cstride.
// 128-row tile/block, 4 waves; wave w: rows w*32..w*32+31 (2 row-tiles).
// STATS=1: per-column sum/sumsq of written values -> gsums (fp64 atomics).
template <int STATS>
__global__ __launch_bounds__(256) void gemm_mfma_kernel(
    const float* __restrict__ A, const short* __restrict__ bhS,
    const short* __restrict__ blS, const float* __restrict__ bias,
    float* __restrict__ C, int cstride, int M, double* __restrict__ gsums) {
  __shared__ float As[128][36];   // row-major, +4 pad
  __shared__ float csum[256];
  const int tid = threadIdx.x;
  const int w = tid >> 6, l = tid & 63;
  const int row0 = blockIdx.x * 128;
  const int lr = l & 15, lg = l >> 4;

  if (STATS) csum[tid] = 0.f;

  f32x4 c[2][8] = {};

  for (int kc = 0; kc < 4; ++kc) {
    __syncthreads();
    // stage A chunk: 128 rows x 32 k fp32
    #pragma unroll
    for (int i = 0; i < 4; ++i) {
      int f = tid + i * 256;            // 0..1023
      int row = f >> 3, k4 = (f & 7) << 2;
      int gr = row0 + row;
      float4 v = make_float4(0.f, 0.f, 0.f, 0.f);
      if (gr < M) v = *(const float4*)(A + (size_t)gr * HD + kc * 32 + k4);
      *(float4*)(&As[row][k4]) = v;
    }
    __syncthreads();

    // A fragments (split to bf16 hi/lo in-register)
    short8v ahi[2], alo[2];
    #pragma unroll
    for (int rt = 0; rt < 2; ++rt) {
      const float* ap = &As[w * 32 + rt * 16 + lr][lg * 8];
      float4 a0 = *(const float4*)ap;
      float4 a1 = *(const float4*)(ap + 4);
      float av[8] = {a0.x, a0.y, a0.z, a0.w, a1.x, a1.y, a1.z, a1.w};
      #pragma unroll
      for (int j = 0; j < 8; ++j) {
        unsigned short h = f2bf_rne(av[j]);
        ahi[rt][j] = (short)h;
        alo[rt][j] = (short)f2bf_rne(av[j] - bf2f(h));
      }
    }

    // B fragments (coalesced 16B, L2-resident) + MFMA
    #pragma unroll
    for (int ct = 0; ct < 8; ++ct) {
      size_t off = ((size_t)(kc * 8 + ct) * 64 + l) * 8;
      short8v bh = *(const short8v*)(bhS + off);
      short8v bl = *(const short8v*)(blS + off);
      #pragma unroll
      for (int rt = 0; rt < 2; ++rt) {
        c[rt][ct] = __builtin_amdgcn_mfma_f32_16x16x32_bf16(ahi[rt], bh, c[rt][ct], 0, 0, 0);
        c[rt][ct] = __builtin_amdgcn_mfma_f32_16x16x32_bf16(alo[rt], bh, c[rt][ct], 0, 0, 0);
        c[rt][ct] = __builtin_amdgcn_mfma_f32_16x16x32_bf16(ahi[rt], bl, c[rt][ct], 0, 0, 0);
        c[rt][ct] = __builtin_amdgcn_mfma_f32_16x16x32_bf16(alo[rt], bl, c[rt][ct], 0, 0, 0);
      }
    }
  }

  // epilogue: bias + relu + store + stats
  // C/D layout: col = lane&15, row = (lane>>4)*4 + reg   [m89-verified]
  float ps[8] = {}, pq[8] = {};
  #pragma unroll
  for (int ct = 0; ct < 8; ++ct) {
    float bv = bias[ct * 16 + lr];
    #pragma unroll
    for (int rt = 0; rt < 2; ++rt) {
      #pragma unroll
      for (int i = 0; i < 4; ++i) {
        int gr = row0 + w * 32 + rt * 16 + lg * 4 + i;
        if (gr < M) {
          float o = fmaxf(c[rt][ct][i] + bv, 0.f);
          C[(size_t)gr * cstride + ct * 16 + lr] = o;
          if (STATS) { ps[ct] += o; pq[ct] += o * o; }
        }
      }
    }
  }

  if (STATS) {
    __syncthreads();
    #pragma unroll
    for (int ct = 0; ct < 8; ++ct) {
      atomicAdd(&csum[ct * 16 + lr], ps[ct]);
      atomicAdd(&csum[128 + ct * 16 + lr], pq[ct]);
    }
    __syncthreads();
    if (tid < 128) {
      atomicAdd(&gsums[tid], (double)csum[tid]);
      atomicAdd(&gsums[HD + tid], (double)csum[128 + tid]);
    }
  }
}

// ----------------------------- BN finalize ---------------------------------
__global__ void zero_d_kernel(double* p) { p[threadIdx.x] = 0.0; }

__global__ void bn_finalize_kernel(const double* __restrict__ sums,
    const float* __restrict__ gamma, const float* __restrict__ beta,
    float* __restrict__ ss) {
  int c = threadIdx.x;                   // 128 threads
  double mu = sums[c] * (1.0 / NN);
  double var = sums[HD + c] * (1.0 / NN) - mu * mu;
  float sc = gamma[c] * (float)(1.0 / sqrt(var + (double)BN_EPS));
  ss[c] = sc;
  ss[HD + c] = beta[c] - (float)mu * sc;
}

// ---------- mean pool over sorted batch ids + per-layer BN affine ----------
__device__ __forceinline__ int lbound(const int* __restrict__ b, int val) {
  int lo = 0, hi = NN;
  while (lo < hi) { int m = (lo + hi) >> 1; if (b[m] < val) lo = m + 1; else hi = m; }
  return lo;
}

__global__ __launch_bounds__(384) void pool_kernel(const int* __restrict__ batch,
    const float* __restrict__ feat, const float* __restrict__ ssAll,
    float* __restrict__ pooled) {
  int g = blockIdx.x;
  int c = threadIdx.x;                   // 0..383
  int l = c >> 7, cc = c & 127;
  float sc = ssAll[l * 256 + cc], sh = ssAll[l * 256 + 128 + cc];
  int lo = lbound(batch, g), hi = lbound(batch, g + 1);
  float s = 0.f;
  for (int r = lo; r < hi; ++r) s += feat[(size_t)r * (NL * HD) + c];
  float inv = 1.f / (float)max(hi - lo, 1);
  pooled[(size_t)g * (NL * HD) + c] = sc * (s * inv) + sh;
}

// ------------------------------- final MLP --------------------------------
__global__ __launch_bounds__(128) void mlp_kernel(const float* __restrict__ pooled,
    const float* __restrict__ W1, const float* __restrict__ b1,
    const float* __restrict__ W2, const float* __restrict__ b2,
    float* __restrict__ out) {
  int g = blockIdx.x, c = threadIdx.x;
  const float* p = pooled + (size_t)g * (NL * HD);
  float acc = b1[c];
  #pragma unroll 4
  for (int k = 0; k < NL * HD; ++k) acc = fmaf(p[k], W1[(size_t)k * HD + c], acc);
  acc = fmaxf(acc, 0.f);
  float prod = acc * W2[c];
  #pragma unroll
  for (int off = 32; off > 0; off >>= 1) prod += __shfl_xor(prod, off, 64);
  __shared__ float part[2];
  if ((c & 63) == 0) part[c >> 6] = prod;
  __syncthreads();
  if (c == 0) out[g] = part[0] + part[1] + b2[0];
}

// -------------------------------- launcher --------------------------------
extern "C" void kernel_launch(void* const* d_in, const int* in_sizes, int n_in,
                              void* d_out, int out_size, void* d_ws, size_t ws_size,
                              hipStream_t stream) {
  (void)in_sizes; (void)n_in; (void)out_size; (void)ws_size;
  const int*   z     = (const int*)d_in[0];
  const int*   ei    = (const int*)d_in[1];
  const int*   batch = (const int*)d_in[2];
  const float* ztab  = (const float*)d_in[3];
  const float* W1    = (const float*)d_in[4];
  const float* b1    = (const float*)d_in[5];
  const float* W2    = (const float*)d_in[6];
  const float* b2    = (const float*)d_in[7];
  const float* gamma = (const float*)d_in[8];
  const float* beta  = (const float*)d_in[9];
  const float* l1W   = (const float*)d_in[10];
  const float* l1b   = (const float*)d_in[11];
  const float* l2W   = (const float*)d_in[12];
  const float* l2b   = (const float*)d_in[13];
  float* out = (float*)d_out;

  char* w = (char*)d_ws;
  float*  bufA   = (float*)w;  w += (size_t)NN * HD * 4;   // GEMM1 out
  float*  bufB   = (float*)w;  w += (size_t)NN * HD * 4;   // agg out
  float*  feat   = (float*)w;  w += (size_t)NN * (NL * HD) * 4; // pre-BN h
  float*  pooled = (float*)w;  w += (size_t)NG * (NL * HD) * 4;
  double* sums   = (double*)w; w += 256 * 8;
  float*  ssAll  = (float*)w;  w += (size_t)NL * 256 * 4;
  int*    rowptr = (int*)w;    w += (size_t)(NN + 1) * 4;
  int*    counts = (int*)w;    w += (size_t)NN * 4;
  int*    filloff= (int*)w;    w += (size_t)NN * 4;
  int*    esrc   = (int*)w;    w += (size_t)NE * 4;
  int*    bsums  = (int*)w;    w += (size_t)cdiv(NN, SCAN_CHUNK) * 4;
  short*  bfragH = (short*)w;  w += 2048 * 8 * 2;          // 32 KB
  short*  bfragL = (short*)w;  w += 2048 * 8 * 2;
  // esrcz ALIASES bufA: written by fill_kernel, read only by layer-0 agg
  // (which writes bufB); bufA is first written later (GEMM1 output, l=0).
  int* esrcz = (int*)bufA;

  const int* srcI = ei;
  const int* dstI = ei + NE;

  dim3 blk(256);
  const int g_nn = cdiv(NN, 256);
  const int g_ne = cdiv(NE, 256);
  const int nb_scan = cdiv(NN, SCAN_CHUNK);
  const int g_gemm = cdiv(NN, 128);      // 782

  // ---- CSR build (graph is layer-invariant: build once per launch) ----
  zero_counts_kernel<<<g_nn, blk, 0, stream>>>(counts);
  hist_kernel<<<g_ne, blk, 0, stream>>>(dstI, counts);
  scan_block_kernel<<<nb_scan, blk, 0, stream>>>(counts, rowptr, bsums);
  scan_bsums_kernel<<<1, 64, 0, stream>>>(bsums, nb_scan);
  scan_add_kernel<<<g_nn, blk, 0, stream>>>(rowptr, bsums, filloff);
  fill_kernel<<<g_ne, blk, 0, stream>>>(srcI, dstI, z, filloff, esrc, esrcz);

  for (int l = 0; l < NL; ++l) {
    if (l == 0) {
      agg_kernel<<<cdiv(NN, 4), blk, 0, stream>>>(rowptr, esrcz, ztab, HD,
                                                  z, nullptr, bufB);
    } else {
      agg_kernel<<<cdiv(NN, 4), blk, 0, stream>>>(rowptr, esrc,
          feat + (l - 1) * HD, NL * HD, nullptr, ssAll + (l - 1) * 256, bufB);
    }
    bsplit_kernel<<<8, blk, 0, stream>>>(W1 + (size_t)l * HD * HD, bfragH, bfragL);
    gemm_mfma_kernel<0><<<g_gemm, blk, 0, stream>>>(bufB, bfragH, bfragL,
        b1 + l * HD, bufA, HD, NN, nullptr);
    zero_d_kernel<<<1, 256, 0, stream>>>(sums);
    bsplit_kernel<<<8, blk, 0, stream>>>(W2 + (size_t)l * HD * HD, bfragH, bfragL);
    gemm_mfma_kernel<1><<<g_gemm, blk, 0, stream>>>(bufA, bfragH, bfragL,
        b2 + l * HD, feat + l * HD, NL * HD, NN, sums);
    bn_finalize_kernel<<<1, 128, 0, stream>>>(sums, gamma + l * HD,
                                              beta + l * HD, ssAll + l * 256);
  }

  pool_kernel<<<NG, 384, 0, stream>>>(batch, feat, ssAll, pooled);
  mlp_kernel<<<NG, 128, 0, stream>>>(pooled, l1W, l1b, l2W, l2b, out);
}